// Round 18
// baseline (739.836 us; speedup 1.0000x reference)
//
#include <hip/hip_runtime.h>
#include <stdint.h>

// ---------------------------------------------------------------------------
// Detector_54365696032903 — full forward implementation.
// B=4, L=24, T=400, D=1024, H=512, G=4 (group size 6), heads=2, Dh=256.
// R1: split-K bias_fold. R2: attn occupancy + XCD remap + V transpose kernel.
// R3: wave-per-output GEMV. R4: XCD-chunked bm-major remap.
// R5: global_load_lds staging + both-sides swizzle. R6 FAILED: vmcnt graft.
// R7: tail compaction. R8/R9/R10: merged MLP gemms + pair tiling + bm-major.
// R11: branchless erf. R12: gemm launch_bounds (256,4); R13: attn (256,2).
// R14: time-pool fused into attn epilogue; LN commuted through QKV gemm: 721us.
// R15 FAILED: s_setprio in lockstep attn. R16: revert to R14 (720.7us).
// R17: attn_fwd K/V staging -> global_load_lds with pre-swizzled per-lane
//      SOURCE + linear LDS dest (rule #21 involution, same pattern as the
//      gemm since R5; m151: gload_lds 874 vs reg-staging 646 TF). Drops
//      stg[] register arrays (VGPR 148 -> ~125) + staging VALU/ds_writes.
// ---------------------------------------------------------------------------

typedef float f32x4 __attribute__((ext_vector_type(4)));
typedef short bf16x8 __attribute__((ext_vector_type(8)));

__device__ __forceinline__ float bf2f(unsigned short u) {
  return __uint_as_float(((unsigned int)u) << 16);
}
__device__ __forceinline__ unsigned short f2bf(float f) {
  unsigned int u = __float_as_uint(f);
  u += 0x7fffu + ((u >> 16) & 1u);
  return (unsigned short)(u >> 16);
}
// Branchless erf, Abramowitz-Stegun 7.1.26 (max abs err 1.5e-7).
__device__ __forceinline__ float erf_fast(float x) {
  const float ax = fabsf(x);
  const float t = 1.0f / fmaf(0.3275911f, ax, 1.0f);
  float p = fmaf(1.061405429f, t, -1.453152027f);
  p = fmaf(p, t, 1.421413741f);
  p = fmaf(p, t, -0.284496736f);
  p = fmaf(p, t, 0.254829592f);
  const float e = __expf(-ax * ax);
  const float r = 1.0f - p * t * e;
  return copysignf(r, x);
}
__device__ __forceinline__ float gelu_f(float x) {
  return 0.5f * x * (1.0f + erf_fast(x * 0.70710678118654752440f));
}

// async global->LDS, 16 B per lane. LDS dest = wave-uniform base + lane*16.
typedef __attribute__((address_space(1))) const unsigned int gas_u32;
typedef __attribute__((address_space(3))) unsigned int las_u32;
__device__ __forceinline__ void gload16(const unsigned short* g, unsigned short* l) {
  __builtin_amdgcn_global_load_lds((gas_u32*)g, (las_u32*)l, 16, 0, 0);
}

// ---------------------------------------------------------------------------
// GEMM: C[M,N] = epi(A[M,K](bf16) @ WT[N,K]^T(bf16) + bias[N])
// 128x128 tile, BK=32, 4 waves (2x2), 16x16x32 MFMA, dbuf global_load_lds
// staging, both-sides swizzle. XCD-chunked bijective remap, bm-major decode.
// GROUPED: grid.z = 16 (b,grp) pairs, Mslice=2400; per-l bias/alpha in
// epilogue (l=(row/400)%24, hoisted per row).
// EPI: 0 bias | 1 bias+GELU | 3 qkv split | 4 merged L1 | 5 merged L2 |
//      6 qkv split with commuted row-LN: v = rstd*acc + bias - rstd*mu*csP
//        (bias2 = float2 row stats (mu,rstd); alpha_vec = colsum(pinT))
// ---------------------------------------------------------------------------
template <int EPI, int GROUPED>
__global__ __launch_bounds__(256, 4) void gemm_bt(
    const unsigned short* __restrict__ A, const unsigned short* __restrict__ WT,
    const float* __restrict__ bias, unsigned short* __restrict__ Cout,
    const unsigned short* __restrict__ WT2, const float* __restrict__ bias2,
    const float* __restrict__ alpha_vec, unsigned short* __restrict__ vtbuf, int K,
    int N, int ldout, int Mslice) {
  const int tid = (int)threadIdx.x;
  const int w = tid >> 6, lane = tid & 63, g = lane >> 4, ql = lane & 15;
  const int wr = w >> 1, wc = w & 1;

  int bm, bn, z = 0;
  if (!GROUPED) {
    const int nbm = (int)gridDim.x, nbn = (int)gridDim.y;
    const int nb = nbm * nbn;
    const int lin = (int)blockIdx.x + nbm * (int)blockIdx.y;
    const int q = nb >> 3, r8 = nb & 7;
    const int xcd = lin & 7, c = lin >> 3;
    const int base = (xcd < r8) ? xcd * (q + 1) : r8 * (q + 1) + (xcd - r8) * q;
    const int widx = base + c;
    bm = widx / nbn;
    bn = widx - bm * nbn;
  } else {
    const int nbm = (int)gridDim.x, nbn = (int)gridDim.y;
    const int per_z = nbm * nbn;
    const int nb = per_z * (int)gridDim.z;
    const int lin =
        (int)blockIdx.x + nbm * ((int)blockIdx.y + (int)gridDim.y * (int)blockIdx.z);
    const int q = nb >> 3, r8 = nb & 7;
    const int xcd = lin & 7, c = lin >> 3;
    const int base = (xcd < r8) ? xcd * (q + 1) : r8 * (q + 1) + (xcd - r8) * q;
    const int widx = base + c;
    z = widx / per_z;
    const int rem = widx - z * per_z;
    bm = rem / nbn;
    bn = rem - bm * nbn;
  }
  const int n0 = bn * 128;

  int rowbase, rows_here;
  int nw0 = n0;
  const unsigned short* wt = WT;
  const float* bs = bias;
  if (GROUPED) {
    const int grp = z & 3;  // z = b*4 + grp
    rowbase = z * Mslice + bm * 128;
    rows_here = Mslice - bm * 128;
    if (rows_here > 128) rows_here = 128;
    if (EPI == 4) {
      if (bn >= 4) {  // group half of N=1024
        wt = WT2 + (size_t)grp * 512 * (size_t)K;
        bs = bias2 + (size_t)grp * 512;
        nw0 = n0 - 512;
      }
    } else if (EPI == 5) {
      wt = WT + (size_t)grp * (size_t)N * (size_t)K;
    } else {
      wt = WT + (size_t)grp * (size_t)N * (size_t)K;
      bs = bias + (size_t)grp * (size_t)N;
    }
  } else {
    rowbase = bm * 128;
    rows_here = Mslice - bm * 128;
    if (rows_here > 128) rows_here = 128;
  }

  // [2 bufs][128 rows][32 shorts] linear (8 KB per tile per buf)
  __shared__ __align__(16) unsigned short sA[2][128 * 32];
  __shared__ __align__(16) unsigned short sB[2][128 * 32];

  f32x4 acc[4][4];
#pragma unroll
  for (int i = 0; i < 4; ++i)
#pragma unroll
    for (int j = 0; j < 4; ++j) acc[i][j] = (f32x4){0.f, 0.f, 0.f, 0.f};

  // staging: wave w stages rows [w*32, w*32+32); source granule pre-swizzled.
  const int swzg = (lane & 3) ^ ((lane >> 3) & 3);
  const int rA0 = w * 32 + (lane >> 2);
  const int rA1 = rA0 + 16;
  const int rA0c = rA0 < rows_here ? rA0 : rows_here - 1;
  const int rA1c = rA1 < rows_here ? rA1 : rows_here - 1;
  const unsigned short* a0p = A + (size_t)(rowbase + rA0c) * K + swzg * 8;
  const unsigned short* a1p = A + (size_t)(rowbase + rA1c) * K + swzg * 8;
  const unsigned short* b0p = wt + (size_t)(nw0 + rA0) * K + swzg * 8;
  const unsigned short* b1p = wt + (size_t)(nw0 + rA1) * K + swzg * 8;
  const int ldsw = w * 1024;

  // fragment read offsets (shorts), swizzled: col granule = g ^ ((ql>>1)&3)
  const int aroff = (wr * 64 + ql) * 32 + ((g ^ ((ql >> 1) & 3)) * 8);
  const int broff = (wc * 64 + ql) * 32 + ((g ^ ((ql >> 1) & 3)) * 8);

  const int nsteps = K >> 5;
  // prologue: stage step 0 into buf 0
  gload16(a0p, &sA[0][ldsw]);
  gload16(a1p, &sA[0][ldsw + 512]);
  gload16(b0p, &sB[0][ldsw]);
  gload16(b1p, &sB[0][ldsw + 512]);
  __syncthreads();

  for (int s = 0; s < nsteps; ++s) {
    const int cur = s & 1;
    if (s + 1 < nsteps) {
      const int k0 = (s + 1) << 5;
      const int nxt = cur ^ 1;
      gload16(a0p + k0, &sA[nxt][ldsw]);
      gload16(a1p + k0, &sA[nxt][ldsw + 512]);
      gload16(b0p + k0, &sB[nxt][ldsw]);
      gload16(b1p + k0, &sB[nxt][ldsw + 512]);
    }
    bf16x8 af[4], bfr[4];
#pragma unroll
    for (int mi = 0; mi < 4; ++mi)
      af[mi] = *(const bf16x8*)(&sA[cur][aroff + mi * 512]);
#pragma unroll
    for (int ni = 0; ni < 4; ++ni)
      bfr[ni] = *(const bf16x8*)(&sB[cur][broff + ni * 512]);
#pragma unroll
    for (int mi = 0; mi < 4; ++mi)
#pragma unroll
      for (int ni = 0; ni < 4; ++ni)
        acc[mi][ni] =
            __builtin_amdgcn_mfma_f32_16x16x32_bf16(af[mi], bfr[ni], acc[mi][ni], 0, 0, 0);
    __syncthreads();  // drains vmcnt(0): next-step stage complete, reads done
  }

  // epilogue: row-major iteration, per-row hoists
#pragma unroll
  for (int mi = 0; mi < 4; ++mi) {
#pragma unroll
    for (int r = 0; r < 4; ++r) {
      const int rloc = wr * 64 + mi * 16 + 4 * g + r;
      if (rloc >= rows_here) continue;
      const int grow = rowbase + rloc;
      float alpha_r = 1.f;
      float mu_r = 0.f, rstd_r = 1.f;
      const float* b2row = bias2;
      if (GROUPED && (EPI == 4 || EPI == 5)) {
        const int l_idx = (grow / 400) % 24;
        if (EPI == 5) b2row = bias2 + (size_t)l_idx * 512;
        if (EPI == 4) alpha_r = alpha_vec[l_idx];
      }
      if (EPI == 6) {
        const float2 strow = ((const float2*)bias2)[grow];
        mu_r = strow.x;
        rstd_r = strow.y;
      }
#pragma unroll
      for (int ni = 0; ni < 4; ++ni) {
        const int col = n0 + wc * 64 + ni * 16 + ql;
        const int colw = (EPI == 4 && bn >= 4) ? (col - 512) : col;
        float v;
        if (EPI == 5) {
          v = acc[mi][ni][r] + b2row[col];
        } else if (EPI == 6) {
          v = rstd_r * acc[mi][ni][r] + (bs[col] - rstd_r * mu_r * alpha_vec[col]);
        } else {
          v = acc[mi][ni][r] + bs[colw];
        }
        if (EPI == 1 || EPI == 4) v = gelu_f(v);
        if (EPI == 4 && bn >= 4) v *= alpha_r;
        if (EPI == 3 || EPI == 6) {
          if (col < 1024) {
            Cout[(size_t)grow * ldout + col] = f2bf(v);
          } else {
            vtbuf[(size_t)grow * 512 + (col - 1024)] = f2bf(v);
          }
        } else {
          Cout[(size_t)grow * ldout + col] = f2bf(v);
        }
      }
    }
  }
}

// ---------------------------------------------------------------------------
// V transpose: vbuf [Ns*400][512] (cols = h*256+d) -> vt [(n*2+h)*256+d][400].
// ---------------------------------------------------------------------------
__global__ void transpose_v(const unsigned short* __restrict__ vbuf,
                            unsigned short* __restrict__ vt) {
  const int p = blockIdx.z;
  const int h = p & 1, nst = p >> 1;
  const int t0 = blockIdx.x * 32, d0 = blockIdx.y * 32;
  __shared__ unsigned short tile[32][33];
  const int tx = threadIdx.x, ty = threadIdx.y;
#pragma unroll
  for (int i = 0; i < 4; ++i) {
    const int t = t0 + ty + i * 8;
    if (t < 400)
      tile[ty + i * 8][tx] = vbuf[((size_t)nst * 400 + t) * 512 + h * 256 + d0 + tx];
  }
  __syncthreads();
  const int t = t0 + tx;
  if (t < 400) {
#pragma unroll
    for (int i = 0; i < 4; ++i)
      vt[((size_t)p * 256 + d0 + ty + i * 8) * 400 + t] = tile[tx][ty + i * 8];
  }
}

// ---------------------------------------------------------------------------
// Attention: flat grid nb = 14*Ns blocks, XCD-chunk-remapped.
// R14: fused time-pooling epilogue. R17: K/V staging via global_load_lds:
// linear LDS dest (wave-uniform base, lane*16 implicit) + pre-swizzled
// per-lane global source slot sslot = (lane&3) ^ ((row>>1)&3); read-side
// XOR unchanged -> identical LDS contents, no VGPR round-trip.
// ---------------------------------------------------------------------------
__global__ __launch_bounds__(256, 2) void attn_fwd(const unsigned short* __restrict__ qk,
                                                   const unsigned short* __restrict__ vt,
                                                   float* __restrict__ pool_part) {
  const int nb = (int)gridDim.x;  // multiple of 8
  int flat = (int)blockIdx.x;
  flat = (flat & 7) * (nb >> 3) + (flat >> 3);  // XCD-chunked remap (bijective)
  const int qt = flat % 7;
  const int h = (flat / 7) & 1;
  const int n = flat / 14;
  const int q0 = qt * 64;

  const int tid = (int)threadIdx.x;
  const int w = tid >> 6, lane = tid & 63, g = lane >> 4, ql = lane & 15;
  const int lr = lane >> 2, lslot = lane & 3;  // R17 staging decomposition

  __shared__ __align__(16) unsigned short slab[400 * 32];  // 25600 B
  __shared__ __align__(16) unsigned short Pc[4][512];      // 4096 B (per-wave 16x32)
  __shared__ float rs[4][16];
  __shared__ float psum[4][256];                           // 4096 B (R14 pooling)

  const int qr = q0 + w * 16 + ql;
  const int qrc = qr < 400 ? qr : 399;
  const unsigned short* qp = qk + ((size_t)n * 400 + qrc) * 1024 + h * 256 + g * 8;
  bf16x8 qf[8];
#pragma unroll
  for (int d0 = 0; d0 < 8; ++d0) qf[d0] = *(const bf16x8*)(qp + d0 * 32);

  f32x4 st[25];
#pragma unroll
  for (int kf = 0; kf < 25; ++kf) st[kf] = (f32x4){0.f, 0.f, 0.f, 0.f};

  const unsigned short* kbase = qk + (size_t)n * 400 * 1024 + 512 + h * 256;
  for (int d0 = 0; d0 < 8; ++d0) {
    __syncthreads();  // prior slab reads complete (all waves)
#pragma unroll
    for (int c = 0; c < 7; ++c) {
      const int base_r = c * 64 + w * 16;  // wave-uniform
      if (base_r + 16 <= 400) {            // wave-uniform validity
        const int r = base_r + lr;
        const int sslot = lslot ^ ((r >> 1) & 3);  // pre-swizzled source
        gload16(kbase + (size_t)r * 1024 + d0 * 32 + sslot * 8,
                slab + base_r * 32);
      }
    }
    __syncthreads();  // drains vmcnt(0): K slab present
#pragma unroll
    for (int kf = 0; kf < 25; ++kf) {
      const int r = kf * 16 + ql;
      bf16x8 kfr = *(const bf16x8*)(slab + r * 32 + ((g ^ ((r >> 1) & 3)) * 8));
      st[kf] = __builtin_amdgcn_mfma_f32_16x16x32_bf16(kfr, qf[d0], st[kf], 0, 0, 0);
    }
  }

  // softmax over k for q = ql (cross-lane only over g via xor 16/32)
  const float sc = 0.0625f;  // 1/sqrt(256)
  float m = -3.0e38f;
#pragma unroll
  for (int kf = 0; kf < 25; ++kf)
    m = fmaxf(m, fmaxf(fmaxf(st[kf][0], st[kf][1]), fmaxf(st[kf][2], st[kf][3])));
  m = fmaxf(m, __shfl_xor(m, 16));
  m = fmaxf(m, __shfl_xor(m, 32));
  float sum = 0.f;
  uint2 pp[25];  // P packed bf16
#pragma unroll
  for (int kf = 0; kf < 25; ++kf) {
    float e0 = __expf((st[kf][0] - m) * sc);
    float e1 = __expf((st[kf][1] - m) * sc);
    float e2 = __expf((st[kf][2] - m) * sc);
    float e3 = __expf((st[kf][3] - m) * sc);
    sum += (e0 + e1) + (e2 + e3);
    pp[kf].x = (unsigned int)f2bf(e0) | ((unsigned int)f2bf(e1) << 16);
    pp[kf].y = (unsigned int)f2bf(e2) | ((unsigned int)f2bf(e3) << 16);
  }
  sum += __shfl_xor(sum, 16);
  sum += __shfl_xor(sum, 32);
  if (g == 0) rs[w][ql] = sum;

  f32x4 oacc[16];
#pragma unroll
  for (int nf = 0; nf < 16; ++nf) oacc[nf] = (f32x4){0.f, 0.f, 0.f, 0.f};

  unsigned short* Pw = Pc[w];
  const unsigned short* vbase = vt + (size_t)(n * 2 + h) * 256 * 400;
  for (int kt = 0; kt < 13; ++kt) {
    const int k0 = kt * 32;
    __syncthreads();  // prior slab reads complete
#pragma unroll
    for (int c = 0; c < 4; ++c) {
      const int base_r = c * 64 + w * 16;  // < 256 always (wave-uniform)
      const int r = base_r + lr;
      const int sslot = lslot ^ ((r >> 1) & 3);
      int kc = k0 + sslot * 8;
      if (kc >= 400) kc = 0;  // pad slots: P is 0 there anyway
      gload16(vbase + (size_t)r * 400 + kc, slab + base_r * 32);
    }
    // JIT P chunk (wave-local buffer; no cross-wave dependency)
    {
      const int kf0 = 2 * kt;
      *(uint2*)(Pw + ql * 32 + 4 * g) = pp[kf0];
      uint2 hi = (kf0 + 1 < 25) ? pp[kf0 + 1] : (uint2){0u, 0u};
      *(uint2*)(Pw + ql * 32 + 16 + 4 * g) = hi;
    }
    __syncthreads();  // drains vmcnt + lgkm: V slab + P chunk present
    bf16x8 pa = *(const bf16x8*)(Pw + ql * 32 + g * 8);
#pragma unroll
    for (int nf = 0; nf < 16; ++nf) {
      const int r = nf * 16 + ql;
      bf16x8 vb = *(const bf16x8*)(slab + r * 32 + ((g ^ ((r >> 1) & 3)) * 8));
      oacc[nf] = __builtin_amdgcn_mfma_f32_16x16x32_bf16(pa, vb, oacc[nf], 0, 0, 0);
    }
  }

  const float inv0 = 1.f / rs[w][4 * g + 0];
  const float inv1 = 1.f / rs[w][4 * g + 1];
  const float inv2 = 1.f / rs[w][4 * g + 2];
  const float inv3 = 1.f / rs[w][4 * g + 3];

  // R14: fused time-pooling — column sums over this block's valid q-rows.
#pragma unroll
  for (int nf = 0; nf < 16; ++nf) {
    float s = 0.f;
#pragma unroll
    for (int r = 0; r < 4; ++r) {
      const int qrow = q0 + w * 16 + 4 * g + r;
      const float invr = (r == 0) ? inv0 : (r == 1) ? inv1 : (r == 2) ? inv2 : inv3;
      if (qrow < 400) s += oacc[nf][r] * invr;
    }
    s += __shfl_xor(s, 16);
    s += __shfl_xor(s, 32);
    if (lane < 16) psum[w][nf * 16 + ql] = s;
  }
  __syncthreads();
  if (tid < 256) {
    const float s = psum[0][tid] + psum[1][tid] + psum[2][tid] + psum[3][tid];
    pool_part[((size_t)((n * 2 + h) * 7 + qt)) * 256 + tid] = s;
  }
}

// ---- R14: pooled[n][h*256+d] = (1/400) * sum_qt pool_part[(n*2+h)*7+qt][d]
__global__ void pool_fin(const float* __restrict__ part, float* __restrict__ out,
                         int Ns) {
  const int i = (int)blockIdx.x * 256 + (int)threadIdx.x;
  if (i >= Ns * 512) return;
  const int n = i >> 9, c = i & 511;
  const int h = c >> 8, d = c & 255;
  float s = 0.f;
#pragma unroll
  for (int qt = 0; qt < 7; ++qt)
    s += part[((size_t)((n * 2 + h) * 7 + qt)) * 256 + d];
  out[i] = s * (1.f / 400.f);
}

// ---- R14: per-row (mu, rstd) of a [rows][512] bf16 matrix. 128 thr/row.
__global__ void row_stats(const unsigned short* __restrict__ in,
                          float2* __restrict__ st) {
  const int row = (int)blockIdx.x;
  const int t = (int)threadIdx.x;
  ushort4 v = ((const ushort4*)in)[(size_t)row * 128 + t];
  const float x0 = bf2f(v.x), x1 = bf2f(v.y), x2 = bf2f(v.z), x3 = bf2f(v.w);
  float s1 = x0 + x1 + x2 + x3;
  float s2 = x0 * x0 + x1 * x1 + x2 * x2 + x3 * x3;
  for (int mlane = 1; mlane < 64; mlane <<= 1) {
    s1 += __shfl_xor(s1, mlane);
    s2 += __shfl_xor(s2, mlane);
  }
  __shared__ float red[4];
  if ((t & 63) == 0) {
    red[t >> 6] = s1;
    red[2 + (t >> 6)] = s2;
  }
  __syncthreads();
  if (t == 0) {
    s1 = red[0] + red[1];
    s2 = red[2] + red[3];
    const float mu = s1 * (1.f / 512.f);
    const float var = s2 * (1.f / 512.f) - mu * mu;
    st[row] = make_float2(mu, rsqrtf(var + 1e-5f));
  }
}

// ---- R14: row sums of a [rows][K] bf16 matrix (colsum of pinT). wave/row.
__global__ void row_sum_bf16(const unsigned short* __restrict__ wm,
                             float* __restrict__ out, int K) {
  const int wid = (int)blockIdx.x * 4 + ((int)threadIdx.x >> 6);
  const int lane = (int)threadIdx.x & 63;
  float s = 0.f;
  for (int k = lane; k < K; k += 64) s += bf2f(wm[(size_t)wid * K + k]);
#pragma unroll
  for (int d = 1; d < 64; d <<= 1) s += __shfl_xor(s, d);
  if (lane == 0) out[wid] = s;
}

// ---------------------------------------------------------------------------
// Row LayerNorm. One block per row; blockDim = C/4.
// ---------------------------------------------------------------------------
template <int TIN, int TOUT>
__global__ void ln_rows(const void* __restrict__ inv, void* __restrict__ outv,
                        const float* __restrict__ gam, const float* __restrict__ bet,
                        int C) {
  const int row = blockIdx.x, t = (int)threadIdx.x;
  float x0, x1, x2, x3;
  if (TIN == 0) {
    float4 v = ((const float4*)inv)[(size_t)row * (C >> 2) + t];
    x0 = v.x; x1 = v.y; x2 = v.z; x3 = v.w;
  } else {
    ushort4 v = ((const ushort4*)inv)[(size_t)row * (C >> 2) + t];
    x0 = bf2f(v.x); x1 = bf2f(v.y); x2 = bf2f(v.z); x3 = bf2f(v.w);
  }
  float s1 = x0 + x1 + x2 + x3;
  float s2 = x0 * x0 + x1 * x1 + x2 * x2 + x3 * x3;
  for (int mlane = 1; mlane < 64; mlane <<= 1) {
    s1 += __shfl_xor(s1, mlane);
    s2 += __shfl_xor(s2, mlane);
  }
  __shared__ float red[8];
  const int nw = blockDim.x >> 6;
  if ((t & 63) == 0) {
    red[t >> 6] = s1;
    red[4 + (t >> 6)] = s2;
  }
  __syncthreads();
  s1 = 0.f; s2 = 0.f;
  for (int i = 0; i < nw; ++i) {
    s1 += red[i];
    s2 += red[4 + i];
  }
  const float mu = s1 / C;
  const float var = s2 / C - mu * mu;
  const float rstd = rsqrtf(var + 1e-5f);
  float y0 = (x0 - mu) * rstd, y1 = (x1 - mu) * rstd, y2 = (x2 - mu) * rstd,
        y3 = (x3 - mu) * rstd;
  if (gam) {
    const int c = t * 4;
    y0 = y0 * gam[c + 0] + bet[c + 0];
    y1 = y1 * gam[c + 1] + bet[c + 1];
    y2 = y2 * gam[c + 2] + bet[c + 2];
    y3 = y3 * gam[c + 3] + bet[c + 3];
  }
  if (TOUT == 0) {
    ushort4 o;
    o.x = f2bf(y0); o.y = f2bf(y1); o.z = f2bf(y2); o.w = f2bf(y3);
    ((ushort4*)outv)[(size_t)row * (C >> 2) + t] = o;
  } else {
    float4 o;
    o.x = y0; o.y = y1; o.z = y2; o.w = y3;
    ((float4*)outv)[(size_t)row * (C >> 2) + t] = o;
  }
}

// W [K][N] f32 -> WT [N][K] bf16, optional per-k scale (LN gamma fold).
__global__ void transpose_w(const float* __restrict__ W, const float* __restrict__ scale,
                            unsigned short* __restrict__ WT, int K, int N) {
  __shared__ float tile[32][33];
  const int k0 = blockIdx.x * 32, n0 = blockIdx.y * 32, zg = blockIdx.z;
  const float* Wz = W + (size_t)zg * K * N;
  const float* sz = scale ? scale + (size_t)zg * K : (const float*)0;
  unsigned short* WTz = WT + (size_t)zg * (size_t)K * N;
  const int tx = threadIdx.x, ty = threadIdx.y;
#pragma unroll
  for (int i = 0; i < 4; ++i)
    tile[ty + i * 8][tx] = Wz[(size_t)(k0 + ty + i * 8) * N + n0 + tx];
  __syncthreads();
#pragma unroll
  for (int i = 0; i < 4; ++i) {
    const int nn = n0 + ty + i * 8;
    const int kk = k0 + tx;
    float v = tile[tx][ty + i * 8];
    if (sz) v *= sz[kk];
    WTz[(size_t)nn * K + kk] = f2bf(v);
  }
}

// W [K][N] f32 -> WT [N][K] f32 (for wave-GEMV weight layout).
__global__ void transpose_wf(const float* __restrict__ W, float* __restrict__ WT, int K,
                             int N) {
  __shared__ float tile[32][33];
  const int k0 = blockIdx.x * 32, n0 = blockIdx.y * 32;
  const int tx = threadIdx.x, ty = threadIdx.y;
#pragma unroll
  for (int i = 0; i < 4; ++i) {
    const int k = k0 + ty + i * 8;
    if (k < K && n0 + tx < N) tile[ty + i * 8][tx] = W[(size_t)k * N + n0 + tx];
  }
  __syncthreads();
#pragma unroll
  for (int i = 0; i < 4; ++i) {
    const int nn = n0 + ty + i * 8;
    const int kk = k0 + tx;
    if (nn < N && kk < K) WT[(size_t)nn * K + kk] = tile[tx][ty + i * 8];
  }
}

// ---- wcomb2[grp][n][k] = k<512 ? sw2T[n][k] : gw2T[grp][n][k-512]
__global__ void build_wcomb2(const unsigned short* __restrict__ sw2T,
                             const unsigned short* __restrict__ gw2T,
                             unsigned short* __restrict__ wc) {
  const int q = (int)blockIdx.x * 256 + (int)threadIdx.x;  // quad idx
  if (q >= 4 * 512 * 256) return;
  const int grp = q / (512 * 256);
  const int rem = q - grp * (512 * 256);
  const int n = rem >> 8, kq = rem & 255;
  ushort4 v;
  if (kq < 128) {
    v = ((const ushort4*)sw2T)[(size_t)n * 128 + kq];
  } else {
    v = ((const ushort4*)gw2T)[((size_t)grp * 512 + n) * 128 + (kq - 128)];
  }
  ((ushort4*)wc)[q] = v;
}

// ---- beff2[l][n] = s_b2[n] + alpha[l]*g_b2[l/6][n]. grid 24, block 512.
__global__ void build_beff2(const float* __restrict__ s_b2, const float* __restrict__ g_b2,
                            const float* __restrict__ alpha, float* __restrict__ beff2) {
  const int l = (int)blockIdx.x;
  const int n = (int)threadIdx.x;
  beff2[(size_t)l * 512 + n] = s_b2[n] + alpha[l] * g_b2[(size_t)(l / 6) * 512 + n];
}

// ---- bias_fold, two-stage split-K ----
#define BF_KC 64
__global__ void bias_fold_part(const float* __restrict__ W, const float* __restrict__ lb,
                               float* __restrict__ part, int K, int N) {
  const int zg = blockIdx.z;
  const int n = blockIdx.x * 256 + (int)threadIdx.x;
  const int kc = blockIdx.y;
  const int kpc = K / BF_KC;
  const float* Wz = W + (size_t)zg * K * N;
  const float* lbz = lb + (size_t)zg * K;
  float acc = 0.f;
  const int k1 = (kc + 1) * kpc;
  for (int k = kc * kpc; k < k1; ++k) acc += lbz[k] * Wz[(size_t)k * N + n];
  part[((size_t)zg * BF_KC + kc) * N + n] = acc;
}
__global__ void bias_fold_final(const float* __restrict__ part, const float* __restrict__ b,
                                float* __restrict__ beff, int N) {
  const int zg = blockIdx.y;
  const int n = blockIdx.x * 256 + (int)threadIdx.x;
  float acc = b[(size_t)zg * N + n];
#pragma unroll
  for (int c = 0; c < BF_KC; ++c) acc += part[((size_t)zg * BF_KC + c) * N + n];
  beff[(size_t)zg * N + n] = acc;
}

// ---- hmean_b[b*400+t][c] = bf16(mean_l hbuf[(b*24+l)*400+t][c]), c<512.
__global__ void mean_h(const unsigned short* __restrict__ h,
                       unsigned short* __restrict__ out) {
  const int i = blockIdx.x * 256 + (int)threadIdx.x;  // quad over [4][400][128]
  if (i >= 4 * 400 * 128) return;
  const int b = i / (400 * 128);
  const int rem = i - b * (400 * 128);
  const int t = rem >> 7, c4 = rem & 127;
  float a0 = 0.f, a1 = 0.f, a2 = 0.f, a3 = 0.f;
  for (int l = 0; l < 24; ++l) {
    ushort4 v = *(const ushort4*)(h + ((size_t)(b * 24 + l) * 400 + t) * 1024 + c4 * 4);
    a0 += bf2f(v.x); a1 += bf2f(v.y); a2 += bf2f(v.z); a3 += bf2f(v.w);
  }
  ushort4 o;
  o.x = f2bf(a0 * (1.f / 24.f));
  o.y = f2bf(a1 * (1.f / 24.f));
  o.z = f2bf(a2 * (1.f / 24.f));
  o.w = f2bf(a3 * (1.f / 24.f));
  *(ushort4*)(out + ((size_t)(b * 400 + t)) * 512 + c4 * 4) = o;
}

// ---- mean over T=400, two-stage split-T (fln path).
template <int TIN>
__global__ void mean_t_part(const void* __restrict__ inv, float* __restrict__ part,
                            int Ns) {
  const int bx = (int)blockIdx.x;
  const int n = bx >> 2, cb = bx & 3;
  const int p = (int)blockIdx.y;
  const int c = cb * 128 + (int)threadIdx.x;
  float acc = 0.f;
  const int t0 = p * 50;
  if (TIN) {
    const unsigned short* in = (const unsigned short*)inv;
    for (int t = t0; t < t0 + 50; ++t) acc += bf2f(in[((size_t)n * 400 + t) * 512 + c]);
  } else {
    const float* in = (const float*)inv;
    for (int t = t0; t < t0 + 50; ++t) acc += in[((size_t)n * 400 + t) * 512 + c];
  }
  part[((size_t)p * Ns + n) * 512 + c] = acc;
}
__global__ void mean_t_fin(const float* __restrict__ part, float* __restrict__ out,
                           int Ns) {
  const int i = (int)blockIdx.x * 256 + (int)threadIdx.x;
  if (i >= Ns * 512) return;
  const int n = i >> 9, c = i & 511;
  float acc = 0.f;
#pragma unroll
  for (int p = 0; p < 8; ++p) acc += part[((size_t)p * Ns + n) * 512 + c];
  out[i] = acc * (1.f / 400.f);
}

// ---- fused fusion + LN: fln[b*400+t] = LN(sum_l rw[b,l]*weighted[b,l,t,:])
__global__ void fuse_ln(const unsigned short* __restrict__ wgt,
                        const float* __restrict__ rw, const float* __restrict__ gam,
                        const float* __restrict__ bet, float* __restrict__ fln) {
  const int row = (int)blockIdx.x;  // b*400 + tt
  const int b = row / 400, tt = row - b * 400;
  const int t = (int)threadIdx.x;
  float a0 = 0.f, a1 = 0.f, a2 = 0.f, a3 = 0.f;
  for (int l = 0; l < 24; ++l) {
    const float wv = rw[b * 24 + l];
    ushort4 v = *(const ushort4*)(wgt + ((size_t)(b * 24 + l) * 400 + tt) * 512 + t * 4);
    a0 += wv * bf2f(v.x); a1 += wv * bf2f(v.y);
    a2 += wv * bf2f(v.z); a3 += wv * bf2f(v.w);
  }
  float s1 = a0 + a1 + a2 + a3;
  float s2 = a0 * a0 + a1 * a1 + a2 * a2 + a3 * a3;
  for (int mlane = 1; mlane < 64; mlane <<= 1) {
    s1 += __shfl_xor(s1, mlane);
    s2 += __shfl_xor(s2, mlane);
  }
  __shared__ float red[4];
  if ((t & 63) == 0) {
    red[t >> 6] = s1;
    red[2 + (t >> 6)] = s2;
  }
  __syncthreads();
  s1 = red[0] + red[1];
  s2 = red[2] + red[3];
  const float mu = s1 * (1.f / 512.f);
  const float var = s2 * (1.f / 512.f) - mu * mu;
  const float rstd = rsqrtf(var + 1e-5f);
  const int c = t * 4;
  float4 o;
  o.x = (a0 - mu) * rstd * gam[c + 0] + bet[c + 0];
  o.y = (a1 - mu) * rstd * gam[c + 1] + bet[c + 1];
  o.z = (a2 - mu) * rstd * gam[c + 2] + bet[c + 2];
  o.w = (a3 - mu) * rstd * gam[c + 3] + bet[c + 3];
  ((float4*)fln)[(size_t)row * 128 + t] = o;
}

// ---- fused LN(a)+LN(b) add: one block per row (4 rows), 128 thr.
__global__ void ln2_add(const float* __restrict__ a, const float* __restrict__ bsrc,
                        const float* __restrict__ gam, const float* __restrict__ bet,
                        float* __restrict__ o1, float* __restrict__ o2) {
  const int row = (int)blockIdx.x;
  const int t = (int)threadIdx.x;
  float4 av = ((const float4*)a)[(size_t)row * 128 + t];
  float4 bv = ((const float4*)bsrc)[(size_t)row * 128 + t];
  float s1a = av.x + av.y + av.z + av.w;
  float s2a = av.x * av.x + av.y * av.y + av.z * av.z + av.w * av.w;
  float s1b = bv.x + bv.y + bv.z + bv.w;
  float s2b = bv.x * bv.x + bv.y * bv.y + bv.z * bv.z + bv.w * bv.w;
  for (int mlane = 1; mlane < 64; mlane <<= 1) {
    s1a += __shfl_xor(s1a, mlane);
    s2a += __shfl_xor(s2a, mlane);
    s1b += __shfl_xor(s1b, mlane);
    s2b += __shfl_xor(s2b, mlane);
  }
  __shared__ float red[8];
  if ((t & 63) == 0) {
    const int wv = t >> 6;
    red[wv] = s1a; red[2 + wv] = s2a; red[4 + wv] = s1b; red[6 + wv] = s2b;
  }
  __syncthreads();
  s1a = red[0] + red[1]; s2a = red[2] + red[3];
  s1b = red[4] + red[5]; s2b = red[6] + red[7];
  const float mua = s1a * (1.f / 512.f);
  const float ra = rsqrtf(s2a * (1.f / 512.f) - mua * mua + 1e-5f);
  const float mub = s1b * (1.f / 512.f);
  const float rb = rsqrtf(s2b * (1.f / 512.f) - mub * mub + 1e-5f);
  const int c = t * 4;
  float4 o;
  o.x = ((av.x - mua) * ra * gam[c + 0] + bet[c + 0]) +
        ((bv.x - mub) * rb * gam[c + 0] + bet[c + 0]);
  o.y = ((av.y - mua) * ra * gam[c + 1] + bet[c + 1]) +
        ((bv.y - mub) * rb * gam[c + 1] + bet[c + 1]);
  o.z = ((av.z - mua) * ra * gam[c + 2] + bet[c + 2]) +
        ((bv.z - mub) * rb * gam[c + 2] + bet[c + 2]);
  o.w = ((av.w - mua) * ra * gam[c + 3] + bet[c + 3]) +
        ((bv.w - mub) * rb * gam[c + 3] + bet[c + 3]);
  ((float4*)o1)[(size_t)row * 128 + t] = o;
  ((float4*)o2)[(size_t)row * 128 + t] = o;
}

// ---------------------------------------------------------------------------
// Wave-per-output GEMV.
// ---------------------------------------------------------------------------
template <int WLAYOUT>
__global__ void gemv_wave(const float* __restrict__ A, const float* __restrict__ Wm,
                          const float* __restrict__ b, float* __restrict__ C, int M, int K,
                          int N, int act) {
  const int wid = (int)(blockIdx.x * (blockDim.x >> 6)) + ((int)threadIdx.x >> 6);
  const int lane = (int)threadIdx.x & 63;
  if (wid >= M * N) return;
  const int row = wid / N, col = wid - row * N;
  const float* a = A + (size_t)row * K;
  float acc = 0.f;
  if (WLAYOUT) {
    const float* wt = Wm + (size_t)col * K;
    for (int k = lane; k < K; k += 64) acc += a[k] * wt[k];
  } else {
    for (int k = lane; k < K; k += 64) acc += a[k] * Wm[(size_t)k * N + col];
  }
#pragma unroll
  for (int d = 1; d < 64; d <<= 1) acc += __shfl_xor(acc, d);
  if (lane == 0) {
    acc += b[col];
    if (act) acc = gelu_f(acc);
    C[wid] = acc;
  }
}

__global__ void routing_k(const float* __restrict__ lr, float* __restrict__ o1,
                          float* __restrict__ o2) {
  const int i = (int)threadIdx.x;
  if (i < 96) {
    const float v = 0.5f / (1.f + __expf(-lr[i] * (1.f / 1.75f))) + (0.5f / 24.f);
    o1[i] = v;
    o2[i] = v;
  }
}

// ---------------------------------------------------------------------------
extern "C" void kernel_launch(void* const* d_in, const int* in_sizes, int n_in,
                              void* d_out, int out_size, void* d_ws, size_t ws_size,
                              hipStream_t stream) {
  const float* x = (const float*)d_in[0];
  const float* mlp_alpha = (const float*)d_in[1];
  const float* s_ln_g = (const float*)d_in[2];
  const float* s_ln_b = (const float*)d_in[3];
  const float* s_w1 = (const float*)d_in[4];
  const float* s_b1 = (const float*)d_in[5];
  const float* s_w2 = (const float*)d_in[6];
  const float* s_b2 = (const float*)d_in[7];
  const float* g_ln_g = (const float*)d_in[8];
  const float* g_ln_b = (const float*)d_in[9];
  const float* g_w1 = (const float*)d_in[10];
  const float* g_b1 = (const float*)d_in[11];
  const float* g_w2 = (const float*)d_in[12];
  const float* g_b2 = (const float*)d_in[13];
  const float* p_ln_g = (const float*)d_in[14];
  const float* p_ln_b = (const float*)d_in[15];
  const float* p_in_w = (const float*)d_in[16];
  const float* p_in_b = (const float*)d_in[17];
  const float* p_out_w = (const float*)d_in[18];
  const float* p_out_b = (const float*)d_in[19];
  const float* r_w1 = (const float*)d_in[20];
  const float* r_b1 = (const float*)d_in[21];
  const float* r_w2 = (const float*)d_in[22];
  const float* r_b2 = (const float*)d_in[23];
  const float* pn_g = (const float*)d_in[24];
  const float* pn_b = (const float*)d_in[25];
  const float* pnf_g = (const float*)d_in[26];
  const float* pnf_b = (const float*)d_in[27];
  const float* c_w1 = (const float*)d_in[28];
  const float* c_b1 = (const float*)d_in[29];
  const float* c_w2 = (const float*)d_in[30];
  const float* c_b2 = (const float*)d_in[31];
  const float* c_w3 = (const float*)d_in[32];
  const float* c_b3 = (const float*)d_in[33];

  float* out = (float*)d_out;  // [logits 8][routing 96][fused_all 2048][time_pooled 49152]
  uint8_t* ws = (uint8_t*)d_ws;

  size_t off = 0;
  auto alloc = [&](size_t bytes) -> size_t {
    size_t o = off;
    off += (bytes + 255) & ~(size_t)255;
    return o;
  };
  const size_t off_xhat = alloc(38400ull * 1024 * 2);  // bf16
  const size_t off_h = alloc(38400ull * 1024 * 2);     // bf16 [gelu(sh)|a*gelu(gr)]
  const size_t off_weighted = alloc(38400ull * 512 * 2);
  const size_t off_qk = alloc(38400ull * 1024 * 2);
  const size_t off_pooled = alloc(96ull * 512 * 4);
  const size_t off_rh = alloc(96ull * 128 * 4);
  const size_t off_lr = alloc(96ull * 4);
  const size_t off_rw = alloc(96ull * 4);
  const size_t off_hmean = alloc(1600ull * 512 * 2);
  const size_t off_smb = alloc(1600ull * 512 * 2);
  const size_t off_wn2 = alloc(1600ull * 512 * 2);
  const size_t off_qk2 = alloc(1600ull * 1024 * 2);
  const size_t off_vbuf2 = alloc(1600ull * 512 * 2);
  const size_t off_vt2 = alloc(4ull * 2 * 256 * 400 * 2);
  const size_t off_pooled2 = alloc(4ull * 512 * 4);
  const size_t off_tctx = alloc(4ull * 512 * 4);
  const size_t off_fln = alloc(4ull * 400 * 512 * 4);
  const size_t off_fvec = alloc(4ull * 512 * 4);
  const size_t off_fall = alloc(4ull * 512 * 4);
  const size_t off_c1 = alloc(4ull * 256 * 4);
  const size_t off_c2 = alloc(4ull * 128 * 4);
  const size_t off_sw1T = alloc(512ull * 1024 * 2);
  const size_t off_sw2T = alloc(512ull * 512 * 2);
  const size_t off_gw1T = alloc(4ull * 512 * 1024 * 2);
  const size_t off_gw2T = alloc(4ull * 512 * 512 * 2);
  const size_t off_pinT = alloc(1536ull * 512 * 2);
  const size_t off_wc2 = alloc(4ull * 512 * 1024 * 2);  // wcomb2
  const size_t off_sb1e = alloc(512ull * 4);
  const size_t off_gb1e = alloc(4ull * 512 * 4);
  const size_t off_pinbe = alloc(1536ull * 4);
  const size_t off_beff2 = alloc(24ull * 512 * 4);
  const size_t off_bfp_s = alloc((size_t)BF_KC * 512 * 4);
  const size_t off_bfp_g = alloc(4ull * BF_KC * 512 * 4);
  const size_t off_bfp_p = alloc((size_t)BF_KC * 1536 * 4);
  const size_t off_powT = alloc(512ull * 512 * 4);
  const size_t off_rw1T = alloc(128ull * 512 * 4);
  const size_t off_cw1T = alloc(256ull * 512 * 4);
  const size_t off_cw2T = alloc(128ull * 256 * 4);
  const size_t off_mtp = alloc(8ull * 96 * 512 * 4);
  const size_t off_wstats = alloc(38400ull * 8);       // float2 per row (R14)
  const size_t off_csp = alloc(1536ull * 4);           // colsum(pinT) (R14)
  const size_t off_pp1 = alloc(96ull * 14 * 256 * 4);  // attn pool partials
  const size_t off_pp2 = alloc(4ull * 14 * 256 * 4);
  // overlays (lifetimes disjoint in the launch sequence below)
  const size_t off_vbuf = off_xhat + 38400ull * 512 * 2;// V natural <- xhat 2nd half
  const size_t off_vt = off_h + 38400ull * 512 * 2;     // V^T <- hbuf 2nd half
  if (off > ws_size) return;  // workspace too small: bail cleanly

  unsigned short* xhat = (unsigned short*)(ws + off_xhat);
  unsigned short* hbuf = (unsigned short*)(ws + off_h);
  unsigned short* weighted = (unsigned short*)(ws + off_weighted);
  unsigned short* qk = (unsigned short*)(ws + off_qk);
  unsigned short* vbuf = (unsigned short*)(ws + off_vbuf);
  unsigned short* vt = (unsigned short*)(ws + off_vt);
  float* pooled = (float*)(ws + off_pooled);
  float* rh = (float*)(ws + off_rh);
  float* lr = (float*)(ws + off_lr);
  float* rw = (float*)(ws + off_rw);
  unsigned short* hmean_b = (unsigned short*)(ws + off_hmean);
  unsigned short* smean_b = (unsigned short*)(ws + off_smb);
  unsigned short* wn2 = (unsigned short*)(ws + off_wn2);
  unsigned short* qk2 = (unsigned short*)(ws + off_qk2);
  unsigned short* vbuf2 = (unsigned short*)(ws + off_vbuf2);
  unsigned short* vt2 = (unsigned short*)(ws + off_vt2);
  float* pooled2 = (float*)(ws + off_pooled2);
  float* tctx = (float*)(ws + off_tctx);
  float* fln = (float*)(ws + off_fln);
  float* fvec = (float*)(ws + off_fvec);
  float* fall = (float*)(ws + off_fall);
  float* c1 = (float*)(ws + off_c1);
  float* c2 = (float*)(ws + off_c2);
  unsigned short* sw1T = (unsigned short*)(ws + off_sw1T);
  unsigned short* sw2T = (unsigned short*)(ws + off_sw2T);
  unsigned short* gw1T = (unsigned short*)(ws + off_gw1T);
  unsigned short* gw2T = (unsigned short*)(ws + off_gw2T);
  unsigned short* pinT = (unsigned short*)(ws + off_pinT);
  unsigned short* wcomb2 = (unsigned short*)(ws + off_wc2);
  float* sb1e = (float*)(ws + off_sb1e);
  float* gb1e = (float*)(ws + off_gb1e);
  float* pinbe = (float*)(ws + off_pinbe);
  float* beff2 = (float*)(ws + off_beff2);
  float* bfp_s = (float*)(ws + off_bfp_s);
  float* bfp_g = (float*)(ws + off_bfp_g);
  float* bfp_p = (float*)(ws + off_bfp_p);
  float* powT = (float*)(ws + off_powT);
  float* rw1T = (float*)(ws + off_rw1T);
  float* cw1T = (float*)(ws + off_cw1T);
  float* cw2T = (float*)(ws + off_cw2T);
  float* mtp = (float*)(ws + off_mtp);
  float2* wstats = (float2*)(ws + off_wstats);
  float* csP = (float*)(ws + off_csp);
  float* pp1 = (float*)(ws + off_pp1);
  float* pp2 = (float*)(ws + off_pp2);

  // ---- weight prep
  transpose_w<<<dim3(32, 16, 1), dim3(32, 8), 0, stream>>>(s_w1, s_ln_g, sw1T, 1024, 512);
  transpose_w<<<dim3(16, 16, 1), dim3(32, 8), 0, stream>>>(s_w2, (const float*)0, sw2T, 512, 512);
  transpose_w<<<dim3(32, 16, 4), dim3(32, 8), 0, stream>>>(g_w1, g_ln_g, gw1T, 1024, 512);
  transpose_w<<<dim3(16, 16, 4), dim3(32, 8), 0, stream>>>(g_w2, (const float*)0, gw2T, 512, 512);
  transpose_w<<<dim3(16, 48, 1), dim3(32, 8), 0, stream>>>(p_in_w, p_ln_g, pinT, 512, 1536);
  transpose_wf<<<dim3(16, 16), dim3(32, 8), 0, stream>>>(p_out_w, powT, 512, 512);
  transpose_wf<<<dim3(16, 4), dim3(32, 8), 0, stream>>>(r_w1, rw1T, 512, 128);
  transpose_wf<<<dim3(16, 8), dim3(32, 8), 0, stream>>>(c_w1, cw1T, 512, 256);
  transpose_wf<<<dim3(8, 4), dim3(32, 8), 0, stream>>>(c_w2, cw2T, 256, 128);
  build_wcomb2<<<2048, 256, 0, stream>>>(sw2T, gw2T, wcomb2);
  build_beff2<<<24, 512, 0, stream>>>(s_b2, g_b2, mlp_alpha, beff2);
  row_sum_bf16<<<384, 256, 0, stream>>>(pinT, csP, 512);  // colsum(pinT) (R14)
  bias_fold_part<<<dim3(2, BF_KC, 1), 256, 0, stream>>>(s_w1, s_ln_b, bfp_s, 1024, 512);
  bias_fold_final<<<dim3(2, 1), 256, 0, stream>>>(bfp_s, s_b1, sb1e, 512);
  bias_fold_part<<<dim3(2, BF_KC, 4), 256, 0, stream>>>(g_w1, g_ln_b, bfp_g, 1024, 512);
  bias_fold_final<<<dim3(2, 4), 256, 0, stream>>>(bfp_g, g_b1, gb1e, 512);
  bias_fold_part<<<dim3(6, BF_KC, 1), 256, 0, stream>>>(p_in_w, p_ln_b, bfp_p, 512, 1536);
  bias_fold_final<<<dim3(6, 1), 256, 0, stream>>>(bfp_p, p_in_b, pinbe, 1536);

  // ---- xhat = normalize(x) (no affine; folded)
  ln_rows<0, 0><<<38400, 256, 0, stream>>>(x, xhat, (const float*)0, (const float*)0, 1024);

  // ---- merged MLP layer 1: hbuf = [gelu(xhat@sw1+sb1e) | a_l*gelu(xhat@gw1+gb1e)]
  gemm_bt<4, 1><<<dim3(19, 8, 16), 256, 0, stream>>>(xhat, sw1T, sb1e, hbuf, gw1T, gb1e,
      mlp_alpha, (unsigned short*)0, 1024, 1024, 1024, 2400);

  // ---- merged MLP layer 2: weighted = hbuf @ wcomb2[grp] + beff2[l]
  gemm_bt<5, 1><<<dim3(19, 4, 16), 256, 0, stream>>>(hbuf, wcomb2, (const float*)0,
      weighted, (const unsigned short*)0, beff2, (const float*)0, (unsigned short*)0,
      1024, 512, 512, 2400);

  // ---- shared_mean via mean/matmul commutation: smean = mean_l(h_s)@sw2 + s_b2
  mean_h<<<800, 256, 0, stream>>>(hbuf, hmean_b);
  gemm_bt<0, 0><<<dim3(13, 4, 1), 256, 0, stream>>>(hmean_b, sw2T, s_b2, smean_b,
      (const unsigned short*)0, (const float*)0, (const float*)0, (unsigned short*)0,
      512, 512, 512, 1600);

  // ---- attention pool over weighted (96 streams); LN commuted into gemm (R14)
  row_stats<<<38400, 128, 0, stream>>>(weighted, wstats);
  gemm_bt<6, 0><<<dim3(300, 12, 1), 256, 0, stream>>>(weighted, pinT, pinbe, qk,
      (const unsigned short*)0, (const float*)wstats, csP, vbuf, 512, 1536, 1024,
      38400);
  transpose_v<<<dim3(13, 8, 192), dim3(32, 8), 0, stream>>>(vbuf, vt);
  attn_fwd<<<dim3(14 * 96), 256, 0, stream>>>(qk, vt, pp1);
  pool_fin<<<192, 256, 0, stream>>>(pp1, pooled, 96);
  gemv_wave<1><<<12288, 256, 0, stream>>>(pooled, powT, p_out_b, out + 2152, 96, 512, 512, 0);

  // ---- router
  gemv_wave<1><<<3072, 256, 0, stream>>>(out + 2152, rw1T, r_b1, rh, 96, 512, 128, 1);
  gemv_wave<0><<<24, 256, 0, stream>>>(rh, r_w2, r_b2, lr, 96, 128, 1, 0);
  routing_k<<<1, 128, 0, stream>>>(lr, out + 8, rw);

  // ---- fusion (fused weighted-sum + LN, then split-T mean)
  fuse_ln<<<1600, 128, 0, stream>>>(weighted, rw, pn_g, pn_b, fln);
  mean_t_part<0><<<dim3(4 * 4, 8), 128, 0, stream>>>(fln, mtp, 4);
  mean_t_fin<<<8, 256, 0, stream>>>(mtp, fvec, 4);

  // ---- time_ctx = attn_pool(shared_mean) (4 streams; small path unchanged)
  ln_rows<1, 0><<<1600, 128, 0, stream>>>(smean_b, wn2, (const float*)0, (const float*)0, 512);
  gemm_bt<3, 0><<<dim3(13, 12, 1), 256, 0, stream>>>(wn2, pinT, pinbe, qk2,
      (const unsigned short*)0, (const float*)0, (const float*)0, vbuf2, 512, 1536, 1024,
      1600);
  transpose_v<<<dim3(13, 8, 8), dim3(32, 8), 0, stream>>>(vbuf2, vt2);
  attn_fwd<<<dim3(14 * 4), 256, 0, stream>>>(qk2, vt2, pp2);
  pool_fin<<<8, 256, 0, stream>>>(pp2, pooled2, 4);
  gemv_wave<1><<<512, 256, 0, stream>>>(pooled2, powT, p_out_b, tctx, 4, 512, 512, 0);

  // ---- fused_all = LN(fvec) + LN(tctx)
  ln2_add<<<4, 128, 0, stream>>>(fvec, tctx, pnf_g, pnf_b, out + 104, fall);

  // ---- classifier
  gemv_wave<1><<<256, 256, 0, stream>>>(fall, cw1T, c_b1, c1, 4, 512, 256, 1);
  gemv_wave<1><<<128, 256, 0, stream>>>(c1, cw2T, c_b2, c2, 4, 256, 128, 1);
  gemv_wave<0><<<2, 256, 0, stream>>>(c2, c_w3, c_b3, out, 4, 128, 2, 0);
}

// Round 19
// 718.245 us; speedup vs baseline: 1.0301x; 1.0301x over previous
//
#include <hip/hip_runtime.h>
#include <stdint.h>

// ---------------------------------------------------------------------------
// Detector_54365696032903 — full forward implementation.
// B=4, L=24, T=400, D=1024, H=512, G=4 (group size 6), heads=2, Dh=256.
// R1: split-K bias_fold. R2: attn occupancy + XCD remap + V transpose kernel.
// R3: wave-per-output GEMV. R4: XCD-chunked bm-major remap.
// R5: global_load_lds staging + both-sides swizzle. R6 FAILED: vmcnt graft.
// R7: tail compaction. R8/R9/R10: merged MLP gemms + pair tiling + bm-major.
// R11: branchless erf. R12: gemm launch_bounds (256,4); R13: attn (256,2).
// R14: time-pool fused into attn epilogue; LN commuted through QKV gemm: 721us.
// R15 FAILED: s_setprio in lockstep attn. R16: revert to R14 (720.7us).
// R17 FAILED (720->740): gload_lds in SINGLE-buffered attn slab serializes
//      barrier->issue->vmcnt(0)->MFMA (m151's win needs dbuf prefetch).
// R18: reg-staging restored + explicit T14 issue-early pipeline: stg loads
//      for iter i+1 issued after iter i's ds_writes are consumed, hiding
//      HBM latency under the MFMA cluster in-wave (m214 r277: +17% attn).
// ---------------------------------------------------------------------------

typedef float f32x4 __attribute__((ext_vector_type(4)));
typedef short bf16x8 __attribute__((ext_vector_type(8)));

__device__ __forceinline__ float bf2f(unsigned short u) {
  return __uint_as_float(((unsigned int)u) << 16);
}
__device__ __forceinline__ unsigned short f2bf(float f) {
  unsigned int u = __float_as_uint(f);
  u += 0x7fffu + ((u >> 16) & 1u);
  return (unsigned short)(u >> 16);
}
// Branchless erf, Abramowitz-Stegun 7.1.26 (max abs err 1.5e-7).
__device__ __forceinline__ float erf_fast(float x) {
  const float ax = fabsf(x);
  const float t = 1.0f / fmaf(0.3275911f, ax, 1.0f);
  float p = fmaf(1.061405429f, t, -1.453152027f);
  p = fmaf(p, t, 1.421413741f);
  p = fmaf(p, t, -0.284496736f);
  p = fmaf(p, t, 0.254829592f);
  const float e = __expf(-ax * ax);
  const float r = 1.0f - p * t * e;
  return copysignf(r, x);
}
__device__ __forceinline__ float gelu_f(float x) {
  return 0.5f * x * (1.0f + erf_fast(x * 0.70710678118654752440f));
}

// async global->LDS, 16 B per lane. LDS dest = wave-uniform base + lane*16.
typedef __attribute__((address_space(1))) const unsigned int gas_u32;
typedef __attribute__((address_space(3))) unsigned int las_u32;
__device__ __forceinline__ void gload16(const unsigned short* g, unsigned short* l) {
  __builtin_amdgcn_global_load_lds((gas_u32*)g, (las_u32*)l, 16, 0, 0);
}

// ---------------------------------------------------------------------------
// GEMM: C[M,N] = epi(A[M,K](bf16) @ WT[N,K]^T(bf16) + bias[N])
// 128x128 tile, BK=32, 4 waves (2x2), 16x16x32 MFMA, dbuf global_load_lds
// staging, both-sides swizzle. XCD-chunked bijective remap, bm-major decode.
// GROUPED: grid.z = 16 (b,grp) pairs, Mslice=2400; per-l bias/alpha in
// epilogue (l=(row/400)%24, hoisted per row).
// EPI: 0 bias | 1 bias+GELU | 3 qkv split | 4 merged L1 | 5 merged L2 |
//      6 qkv split with commuted row-LN: v = rstd*acc + bias - rstd*mu*csP
//        (bias2 = float2 row stats (mu,rstd); alpha_vec = colsum(pinT))
// ---------------------------------------------------------------------------
template <int EPI, int GROUPED>
__global__ __launch_bounds__(256, 4) void gemm_bt(
    const unsigned short* __restrict__ A, const unsigned short* __restrict__ WT,
    const float* __restrict__ bias, unsigned short* __restrict__ Cout,
    const unsigned short* __restrict__ WT2, const float* __restrict__ bias2,
    const float* __restrict__ alpha_vec, unsigned short* __restrict__ vtbuf, int K,
    int N, int ldout, int Mslice) {
  const int tid = (int)threadIdx.x;
  const int w = tid >> 6, lane = tid & 63, g = lane >> 4, ql = lane & 15;
  const int wr = w >> 1, wc = w & 1;

  int bm, bn, z = 0;
  if (!GROUPED) {
    const int nbm = (int)gridDim.x, nbn = (int)gridDim.y;
    const int nb = nbm * nbn;
    const int lin = (int)blockIdx.x + nbm * (int)blockIdx.y;
    const int q = nb >> 3, r8 = nb & 7;
    const int xcd = lin & 7, c = lin >> 3;
    const int base = (xcd < r8) ? xcd * (q + 1) : r8 * (q + 1) + (xcd - r8) * q;
    const int widx = base + c;
    bm = widx / nbn;
    bn = widx - bm * nbn;
  } else {
    const int nbm = (int)gridDim.x, nbn = (int)gridDim.y;
    const int per_z = nbm * nbn;
    const int nb = per_z * (int)gridDim.z;
    const int lin =
        (int)blockIdx.x + nbm * ((int)blockIdx.y + (int)gridDim.y * (int)blockIdx.z);
    const int q = nb >> 3, r8 = nb & 7;
    const int xcd = lin & 7, c = lin >> 3;
    const int base = (xcd < r8) ? xcd * (q + 1) : r8 * (q + 1) + (xcd - r8) * q;
    const int widx = base + c;
    z = widx / per_z;
    const int rem = widx - z * per_z;
    bm = rem / nbn;
    bn = rem - bm * nbn;
  }
  const int n0 = bn * 128;

  int rowbase, rows_here;
  int nw0 = n0;
  const unsigned short* wt = WT;
  const float* bs = bias;
  if (GROUPED) {
    const int grp = z & 3;  // z = b*4 + grp
    rowbase = z * Mslice + bm * 128;
    rows_here = Mslice - bm * 128;
    if (rows_here > 128) rows_here = 128;
    if (EPI == 4) {
      if (bn >= 4) {  // group half of N=1024
        wt = WT2 + (size_t)grp * 512 * (size_t)K;
        bs = bias2 + (size_t)grp * 512;
        nw0 = n0 - 512;
      }
    } else if (EPI == 5) {
      wt = WT + (size_t)grp * (size_t)N * (size_t)K;
    } else {
      wt = WT + (size_t)grp * (size_t)N * (size_t)K;
      bs = bias + (size_t)grp * (size_t)N;
    }
  } else {
    rowbase = bm * 128;
    rows_here = Mslice - bm * 128;
    if (rows_here > 128) rows_here = 128;
  }

  // [2 bufs][128 rows][32 shorts] linear (8 KB per tile per buf)
  __shared__ __align__(16) unsigned short sA[2][128 * 32];
  __shared__ __align__(16) unsigned short sB[2][128 * 32];

  f32x4 acc[4][4];
#pragma unroll
  for (int i = 0; i < 4; ++i)
#pragma unroll
    for (int j = 0; j < 4; ++j) acc[i][j] = (f32x4){0.f, 0.f, 0.f, 0.f};

  // staging: wave w stages rows [w*32, w*32+32); source granule pre-swizzled.
  const int swzg = (lane & 3) ^ ((lane >> 3) & 3);
  const int rA0 = w * 32 + (lane >> 2);
  const int rA1 = rA0 + 16;
  const int rA0c = rA0 < rows_here ? rA0 : rows_here - 1;
  const int rA1c = rA1 < rows_here ? rA1 : rows_here - 1;
  const unsigned short* a0p = A + (size_t)(rowbase + rA0c) * K + swzg * 8;
  const unsigned short* a1p = A + (size_t)(rowbase + rA1c) * K + swzg * 8;
  const unsigned short* b0p = wt + (size_t)(nw0 + rA0) * K + swzg * 8;
  const unsigned short* b1p = wt + (size_t)(nw0 + rA1) * K + swzg * 8;
  const int ldsw = w * 1024;

  // fragment read offsets (shorts), swizzled: col granule = g ^ ((ql>>1)&3)
  const int aroff = (wr * 64 + ql) * 32 + ((g ^ ((ql >> 1) & 3)) * 8);
  const int broff = (wc * 64 + ql) * 32 + ((g ^ ((ql >> 1) & 3)) * 8);

  const int nsteps = K >> 5;
  // prologue: stage step 0 into buf 0
  gload16(a0p, &sA[0][ldsw]);
  gload16(a1p, &sA[0][ldsw + 512]);
  gload16(b0p, &sB[0][ldsw]);
  gload16(b1p, &sB[0][ldsw + 512]);
  __syncthreads();

  for (int s = 0; s < nsteps; ++s) {
    const int cur = s & 1;
    if (s + 1 < nsteps) {
      const int k0 = (s + 1) << 5;
      const int nxt = cur ^ 1;
      gload16(a0p + k0, &sA[nxt][ldsw]);
      gload16(a1p + k0, &sA[nxt][ldsw + 512]);
      gload16(b0p + k0, &sB[nxt][ldsw]);
      gload16(b1p + k0, &sB[nxt][ldsw + 512]);
    }
    bf16x8 af[4], bfr[4];
#pragma unroll
    for (int mi = 0; mi < 4; ++mi)
      af[mi] = *(const bf16x8*)(&sA[cur][aroff + mi * 512]);
#pragma unroll
    for (int ni = 0; ni < 4; ++ni)
      bfr[ni] = *(const bf16x8*)(&sB[cur][broff + ni * 512]);
#pragma unroll
    for (int mi = 0; mi < 4; ++mi)
#pragma unroll
      for (int ni = 0; ni < 4; ++ni)
        acc[mi][ni] =
            __builtin_amdgcn_mfma_f32_16x16x32_bf16(af[mi], bfr[ni], acc[mi][ni], 0, 0, 0);
    __syncthreads();  // drains vmcnt(0): next-step stage complete, reads done
  }

  // epilogue: row-major iteration, per-row hoists
#pragma unroll
  for (int mi = 0; mi < 4; ++mi) {
#pragma unroll
    for (int r = 0; r < 4; ++r) {
      const int rloc = wr * 64 + mi * 16 + 4 * g + r;
      if (rloc >= rows_here) continue;
      const int grow = rowbase + rloc;
      float alpha_r = 1.f;
      float mu_r = 0.f, rstd_r = 1.f;
      const float* b2row = bias2;
      if (GROUPED && (EPI == 4 || EPI == 5)) {
        const int l_idx = (grow / 400) % 24;
        if (EPI == 5) b2row = bias2 + (size_t)l_idx * 512;
        if (EPI == 4) alpha_r = alpha_vec[l_idx];
      }
      if (EPI == 6) {
        const float2 strow = ((const float2*)bias2)[grow];
        mu_r = strow.x;
        rstd_r = strow.y;
      }
#pragma unroll
      for (int ni = 0; ni < 4; ++ni) {
        const int col = n0 + wc * 64 + ni * 16 + ql;
        const int colw = (EPI == 4 && bn >= 4) ? (col - 512) : col;
        float v;
        if (EPI == 5) {
          v = acc[mi][ni][r] + b2row[col];
        } else if (EPI == 6) {
          v = rstd_r * acc[mi][ni][r] + (bs[col] - rstd_r * mu_r * alpha_vec[col]);
        } else {
          v = acc[mi][ni][r] + bs[colw];
        }
        if (EPI == 1 || EPI == 4) v = gelu_f(v);
        if (EPI == 4 && bn >= 4) v *= alpha_r;
        if (EPI == 3 || EPI == 6) {
          if (col < 1024) {
            Cout[(size_t)grow * ldout + col] = f2bf(v);
          } else {
            vtbuf[(size_t)grow * 512 + (col - 1024)] = f2bf(v);
          }
        } else {
          Cout[(size_t)grow * ldout + col] = f2bf(v);
        }
      }
    }
  }
}

// ---------------------------------------------------------------------------
// V transpose: vbuf [Ns*400][512] (cols = h*256+d) -> vt [(n*2+h)*256+d][400].
// ---------------------------------------------------------------------------
__global__ void transpose_v(const unsigned short* __restrict__ vbuf,
                            unsigned short* __restrict__ vt) {
  const int p = blockIdx.z;
  const int h = p & 1, nst = p >> 1;
  const int t0 = blockIdx.x * 32, d0 = blockIdx.y * 32;
  __shared__ unsigned short tile[32][33];
  const int tx = threadIdx.x, ty = threadIdx.y;
#pragma unroll
  for (int i = 0; i < 4; ++i) {
    const int t = t0 + ty + i * 8;
    if (t < 400)
      tile[ty + i * 8][tx] = vbuf[((size_t)nst * 400 + t) * 512 + h * 256 + d0 + tx];
  }
  __syncthreads();
  const int t = t0 + tx;
  if (t < 400) {
#pragma unroll
    for (int i = 0; i < 4; ++i)
      vt[((size_t)p * 256 + d0 + ty + i * 8) * 400 + t] = tile[tx][ty + i * 8];
  }
}

// ---------------------------------------------------------------------------
// Attention: flat grid nb = 14*Ns blocks, XCD-chunk-remapped.
// R14: fused time-pooling epilogue. R18: reg-staging with explicit T14
// issue-early pipeline — stg loads for iter i+1 issued right after iter i's
// ds_writes (regs free), hiding HBM latency under the MFMA cluster.
// ---------------------------------------------------------------------------
__global__ __launch_bounds__(256, 2) void attn_fwd(const unsigned short* __restrict__ qk,
                                                   const unsigned short* __restrict__ vt,
                                                   float* __restrict__ pool_part) {
  const int nb = (int)gridDim.x;  // multiple of 8
  int flat = (int)blockIdx.x;
  flat = (flat & 7) * (nb >> 3) + (flat >> 3);  // XCD-chunked remap (bijective)
  const int qt = flat % 7;
  const int h = (flat / 7) & 1;
  const int n = flat / 14;
  const int q0 = qt * 64;

  const int tid = (int)threadIdx.x;
  const int w = tid >> 6, lane = tid & 63, g = lane >> 4, ql = lane & 15;

  __shared__ __align__(16) unsigned short slab[400 * 32];  // 25600 B
  __shared__ __align__(16) unsigned short Pc[4][512];      // 4096 B (per-wave 16x32)
  __shared__ float rs[4][16];
  __shared__ float psum[4][256];                           // 4096 B (R14 pooling)

  const int qr = q0 + w * 16 + ql;
  const int qrc = qr < 400 ? qr : 399;
  const unsigned short* qp = qk + ((size_t)n * 400 + qrc) * 1024 + h * 256 + g * 8;
  bf16x8 qf[8];
#pragma unroll
  for (int d0 = 0; d0 < 8; ++d0) qf[d0] = *(const bf16x8*)(qp + d0 * 32);

  f32x4 st[25];
#pragma unroll
  for (int kf = 0; kf < 25; ++kf) st[kf] = (f32x4){0.f, 0.f, 0.f, 0.f};

  // K phase: pipelined reg-staging (R18)
  const unsigned short* kbase = qk + (size_t)n * 400 * 1024 + 512 + h * 256;
  bf16x8 stg[7];
#pragma unroll
  for (int c = 0; c < 7; ++c) {
    const int q = tid + c * 256;
    const int r = q >> 2, slot = q & 3;
    if (r < 400) stg[c] = *(const bf16x8*)(kbase + (size_t)r * 1024 + slot * 8);
  }
#pragma unroll
  for (int d0 = 0; d0 < 8; ++d0) {
    __syncthreads();  // prior slab reads complete
#pragma unroll
    for (int c = 0; c < 7; ++c) {
      const int q = tid + c * 256;
      const int r = q >> 2, slot = q & 3;
      if (r < 400) *(bf16x8*)(slab + r * 32 + (slot ^ ((r >> 1) & 3)) * 8) = stg[c];
    }
    __syncthreads();  // slab ready
    if (d0 + 1 < 8) {  // issue-early: next-d0 loads overlap the MFMA cluster
#pragma unroll
      for (int c = 0; c < 7; ++c) {
        const int q = tid + c * 256;
        const int r = q >> 2, slot = q & 3;
        if (r < 400)
          stg[c] = *(const bf16x8*)(kbase + (size_t)r * 1024 + (d0 + 1) * 32 + slot * 8);
      }
    }
#pragma unroll
    for (int kf = 0; kf < 25; ++kf) {
      const int r = kf * 16 + ql;
      bf16x8 kfr = *(const bf16x8*)(slab + r * 32 + ((g ^ ((r >> 1) & 3)) * 8));
      st[kf] = __builtin_amdgcn_mfma_f32_16x16x32_bf16(kfr, qf[d0], st[kf], 0, 0, 0);
    }
  }

  // V prologue loads (kt=0) issued here: softmax VALU hides their latency.
  const unsigned short* vbase = vt + (size_t)(n * 2 + h) * 256 * 400;
  bf16x8 vstg[4];
#pragma unroll
  for (int c = 0; c < 4; ++c) {
    const int q = tid + c * 256;
    const int r = q >> 2, slot = q & 3;
    vstg[c] = *(const bf16x8*)(vbase + (size_t)r * 400 + slot * 8);  // kc<400 at kt=0
  }

  // softmax over k for q = ql (cross-lane only over g via xor 16/32)
  const float sc = 0.0625f;  // 1/sqrt(256)
  float m = -3.0e38f;
#pragma unroll
  for (int kf = 0; kf < 25; ++kf)
    m = fmaxf(m, fmaxf(fmaxf(st[kf][0], st[kf][1]), fmaxf(st[kf][2], st[kf][3])));
  m = fmaxf(m, __shfl_xor(m, 16));
  m = fmaxf(m, __shfl_xor(m, 32));
  float sum = 0.f;
  uint2 pp[25];  // P packed bf16
#pragma unroll
  for (int kf = 0; kf < 25; ++kf) {
    float e0 = __expf((st[kf][0] - m) * sc);
    float e1 = __expf((st[kf][1] - m) * sc);
    float e2 = __expf((st[kf][2] - m) * sc);
    float e3 = __expf((st[kf][3] - m) * sc);
    sum += (e0 + e1) + (e2 + e3);
    pp[kf].x = (unsigned int)f2bf(e0) | ((unsigned int)f2bf(e1) << 16);
    pp[kf].y = (unsigned int)f2bf(e2) | ((unsigned int)f2bf(e3) << 16);
  }
  sum += __shfl_xor(sum, 16);
  sum += __shfl_xor(sum, 32);
  if (g == 0) rs[w][ql] = sum;

  f32x4 oacc[16];
#pragma unroll
  for (int nf = 0; nf < 16; ++nf) oacc[nf] = (f32x4){0.f, 0.f, 0.f, 0.f};

  unsigned short* Pw = Pc[w];
#pragma unroll
  for (int kt = 0; kt < 13; ++kt) {
    __syncthreads();  // prior slab reads complete
#pragma unroll
    for (int c = 0; c < 4; ++c) {
      const int q = tid + c * 256;
      const int r = q >> 2, slot = q & 3;
      *(bf16x8*)(slab + r * 32 + (slot ^ ((r >> 1) & 3)) * 8) = vstg[c];
    }
    // JIT P chunk (wave-local buffer; no cross-wave dependency)
    {
      const int kf0 = 2 * kt;
      *(uint2*)(Pw + ql * 32 + 4 * g) = pp[kf0];
      uint2 hi = (kf0 + 1 < 25) ? pp[kf0 + 1] : (uint2){0u, 0u};
      *(uint2*)(Pw + ql * 32 + 16 + 4 * g) = hi;
    }
    __syncthreads();  // slab + P chunk ready
    if (kt + 1 < 13) {  // issue-early: next-kt loads overlap the MFMA cluster
      const int k0n = (kt + 1) * 32;
#pragma unroll
      for (int c = 0; c < 4; ++c) {
        const int q = tid + c * 256;
        const int r = q >> 2, slot = q & 3;
        int kc = k0n + slot * 8;
        if (kc >= 400) kc = 0;  // pad slots: P is 0 there anyway
        vstg[c] = *(const bf16x8*)(vbase + (size_t)r * 400 + kc);
      }
    }
    bf16x8 pa = *(const bf16x8*)(Pw + ql * 32 + g * 8);
#pragma unroll
    for (int nf = 0; nf < 16; ++nf) {
      const int r = nf * 16 + ql;
      bf16x8 vb = *(const bf16x8*)(slab + r * 32 + ((g ^ ((r >> 1) & 3)) * 8));
      oacc[nf] = __builtin_amdgcn_mfma_f32_16x16x32_bf16(pa, vb, oacc[nf], 0, 0, 0);
    }
  }

  const float inv0 = 1.f / rs[w][4 * g + 0];
  const float inv1 = 1.f / rs[w][4 * g + 1];
  const float inv2 = 1.f / rs[w][4 * g + 2];
  const float inv3 = 1.f / rs[w][4 * g + 3];

  // R14: fused time-pooling — column sums over this block's valid q-rows.
#pragma unroll
  for (int nf = 0; nf < 16; ++nf) {
    float s = 0.f;
#pragma unroll
    for (int r = 0; r < 4; ++r) {
      const int qrow = q0 + w * 16 + 4 * g + r;
      const float invr = (r == 0) ? inv0 : (r == 1) ? inv1 : (r == 2) ? inv2 : inv3;
      if (qrow < 400) s += oacc[nf][r] * invr;
    }
    s += __shfl_xor(s, 16);
    s += __shfl_xor(s, 32);
    if (lane < 16) psum[w][nf * 16 + ql] = s;
  }
  __syncthreads();
  if (tid < 256) {
    const float s = psum[0][tid] + psum[1][tid] + psum[2][tid] + psum[3][tid];
    pool_part[((size_t)((n * 2 + h) * 7 + qt)) * 256 + tid] = s;
  }
}

// ---- R14: pooled[n][h*256+d] = (1/400) * sum_qt pool_part[(n*2+h)*7+qt][d]
__global__ void pool_fin(const float* __restrict__ part, float* __restrict__ out,
                         int Ns) {
  const int i = (int)blockIdx.x * 256 + (int)threadIdx.x;
  if (i >= Ns * 512) return;
  const int n = i >> 9, c = i & 511;
  const int h = c >> 8, d = c & 255;
  float s = 0.f;
#pragma unroll
  for (int qt = 0; qt < 7; ++qt)
    s += part[((size_t)((n * 2 + h) * 7 + qt)) * 256 + d];
  out[i] = s * (1.f / 400.f);
}

// ---- R14: per-row (mu, rstd) of a [rows][512] bf16 matrix. 128 thr/row.
__global__ void row_stats(const unsigned short* __restrict__ in,
                          float2* __restrict__ st) {
  const int row = (int)blockIdx.x;
  const int t = (int)threadIdx.x;
  ushort4 v = ((const ushort4*)in)[(size_t)row * 128 + t];
  const float x0 = bf2f(v.x), x1 = bf2f(v.y), x2 = bf2f(v.z), x3 = bf2f(v.w);
  float s1 = x0 + x1 + x2 + x3;
  float s2 = x0 * x0 + x1 * x1 + x2 * x2 + x3 * x3;
  for (int mlane = 1; mlane < 64; mlane <<= 1) {
    s1 += __shfl_xor(s1, mlane);
    s2 += __shfl_xor(s2, mlane);
  }
  __shared__ float red[4];
  if ((t & 63) == 0) {
    red[t >> 6] = s1;
    red[2 + (t >> 6)] = s2;
  }
  __syncthreads();
  if (t == 0) {
    s1 = red[0] + red[1];
    s2 = red[2] + red[3];
    const float mu = s1 * (1.f / 512.f);
    const float var = s2 * (1.f / 512.f) - mu * mu;
    st[row] = make_float2(mu, rsqrtf(var + 1e-5f));
  }
}

// ---- R14: row sums of a [rows][K] bf16 matrix (colsum of pinT). wave/row.
__global__ void row_sum_bf16(const unsigned short* __restrict__ wm,
                             float* __restrict__ out, int K) {
  const int wid = (int)blockIdx.x * 4 + ((int)threadIdx.x >> 6);
  const int lane = (int)threadIdx.x & 63;
  float s = 0.f;
  for (int k = lane; k < K; k += 64) s += bf2f(wm[(size_t)wid * K + k]);
#pragma unroll
  for (int d = 1; d < 64; d <<= 1) s += __shfl_xor(s, d);
  if (lane == 0) out[wid] = s;
}

// ---------------------------------------------------------------------------
// Row LayerNorm. One block per row; blockDim = C/4.
// ---------------------------------------------------------------------------
template <int TIN, int TOUT>
__global__ void ln_rows(const void* __restrict__ inv, void* __restrict__ outv,
                        const float* __restrict__ gam, const float* __restrict__ bet,
                        int C) {
  const int row = blockIdx.x, t = (int)threadIdx.x;
  float x0, x1, x2, x3;
  if (TIN == 0) {
    float4 v = ((const float4*)inv)[(size_t)row * (C >> 2) + t];
    x0 = v.x; x1 = v.y; x2 = v.z; x3 = v.w;
  } else {
    ushort4 v = ((const ushort4*)inv)[(size_t)row * (C >> 2) + t];
    x0 = bf2f(v.x); x1 = bf2f(v.y); x2 = bf2f(v.z); x3 = bf2f(v.w);
  }
  float s1 = x0 + x1 + x2 + x3;
  float s2 = x0 * x0 + x1 * x1 + x2 * x2 + x3 * x3;
  for (int mlane = 1; mlane < 64; mlane <<= 1) {
    s1 += __shfl_xor(s1, mlane);
    s2 += __shfl_xor(s2, mlane);
  }
  __shared__ float red[8];
  const int nw = blockDim.x >> 6;
  if ((t & 63) == 0) {
    red[t >> 6] = s1;
    red[4 + (t >> 6)] = s2;
  }
  __syncthreads();
  s1 = 0.f; s2 = 0.f;
  for (int i = 0; i < nw; ++i) {
    s1 += red[i];
    s2 += red[4 + i];
  }
  const float mu = s1 / C;
  const float var = s2 / C - mu * mu;
  const float rstd = rsqrtf(var + 1e-5f);
  float y0 = (x0 - mu) * rstd, y1 = (x1 - mu) * rstd, y2 = (x2 - mu) * rstd,
        y3 = (x3 - mu) * rstd;
  if (gam) {
    const int c = t * 4;
    y0 = y0 * gam[c + 0] + bet[c + 0];
    y1 = y1 * gam[c + 1] + bet[c + 1];
    y2 = y2 * gam[c + 2] + bet[c + 2];
    y3 = y3 * gam[c + 3] + bet[c + 3];
  }
  if (TOUT == 0) {
    ushort4 o;
    o.x = f2bf(y0); o.y = f2bf(y1); o.z = f2bf(y2); o.w = f2bf(y3);
    ((ushort4*)outv)[(size_t)row * (C >> 2) + t] = o;
  } else {
    float4 o;
    o.x = y0; o.y = y1; o.z = y2; o.w = y3;
    ((float4*)outv)[(size_t)row * (C >> 2) + t] = o;
  }
}

// W [K][N] f32 -> WT [N][K] bf16, optional per-k scale (LN gamma fold).
__global__ void transpose_w(const float* __restrict__ W, const float* __restrict__ scale,
                            unsigned short* __restrict__ WT, int K, int N) {
  __shared__ float tile[32][33];
  const int k0 = blockIdx.x * 32, n0 = blockIdx.y * 32, zg = blockIdx.z;
  const float* Wz = W + (size_t)zg * K * N;
  const float* sz = scale ? scale + (size_t)zg * K : (const float*)0;
  unsigned short* WTz = WT + (size_t)zg * (size_t)K * N;
  const int tx = threadIdx.x, ty = threadIdx.y;
#pragma unroll
  for (int i = 0; i < 4; ++i)
    tile[ty + i * 8][tx] = Wz[(size_t)(k0 + ty + i * 8) * N + n0 + tx];
  __syncthreads();
#pragma unroll
  for (int i = 0; i < 4; ++i) {
    const int nn = n0 + ty + i * 8;
    const int kk = k0 + tx;
    float v = tile[tx][ty + i * 8];
    if (sz) v *= sz[kk];
    WTz[(size_t)nn * K + kk] = f2bf(v);
  }
}

// W [K][N] f32 -> WT [N][K] f32 (for wave-GEMV weight layout).
__global__ void transpose_wf(const float* __restrict__ W, float* __restrict__ WT, int K,
                             int N) {
  __shared__ float tile[32][33];
  const int k0 = blockIdx.x * 32, n0 = blockIdx.y * 32;
  const int tx = threadIdx.x, ty = threadIdx.y;
#pragma unroll
  for (int i = 0; i < 4; ++i) {
    const int k = k0 + ty + i * 8;
    if (k < K && n0 + tx < N) tile[ty + i * 8][tx] = W[(size_t)k * N + n0 + tx];
  }
  __syncthreads();
#pragma unroll
  for (int i = 0; i < 4; ++i) {
    const int nn = n0 + ty + i * 8;
    const int kk = k0 + tx;
    if (nn < N && kk < K) WT[(size_t)nn * K + kk] = tile[tx][ty + i * 8];
  }
}

// ---- wcomb2[grp][n][k] = k<512 ? sw2T[n][k] : gw2T[grp][n][k-512]
__global__ void build_wcomb2(const unsigned short* __restrict__ sw2T,
                             const unsigned short* __restrict__ gw2T,
                             unsigned short* __restrict__ wc) {
  const int q = (int)blockIdx.x * 256 + (int)threadIdx.x;  // quad idx
  if (q >= 4 * 512 * 256) return;
  const int grp = q / (512 * 256);
  const int rem = q - grp * (512 * 256);
  const int n = rem >> 8, kq = rem & 255;
  ushort4 v;
  if (kq < 128) {
    v = ((const ushort4*)sw2T)[(size_t)n * 128 + kq];
  } else {
    v = ((const ushort4*)gw2T)[((size_t)grp * 512 + n) * 128 + (kq - 128)];
  }
  ((ushort4*)wc)[q] = v;
}

// ---- beff2[l][n] = s_b2[n] + alpha[l]*g_b2[l/6][n]. grid 24, block 512.
__global__ void build_beff2(const float* __restrict__ s_b2, const float* __restrict__ g_b2,
                            const float* __restrict__ alpha, float* __restrict__ beff2) {
  const int l = (int)blockIdx.x;
  const int n = (int)threadIdx.x;
  beff2[(size_t)l * 512 + n] = s_b2[n] + alpha[l] * g_b2[(size_t)(l / 6) * 512 + n];
}

// ---- bias_fold, two-stage split-K ----
#define BF_KC 64
__global__ void bias_fold_part(const float* __restrict__ W, const float* __restrict__ lb,
                               float* __restrict__ part, int K, int N) {
  const int zg = blockIdx.z;
  const int n = blockIdx.x * 256 + (int)threadIdx.x;
  const int kc = blockIdx.y;
  const int kpc = K / BF_KC;
  const float* Wz = W + (size_t)zg * K * N;
  const float* lbz = lb + (size_t)zg * K;
  float acc = 0.f;
  const int k1 = (kc + 1) * kpc;
  for (int k = kc * kpc; k < k1; ++k) acc += lbz[k] * Wz[(size_t)k * N + n];
  part[((size_t)zg * BF_KC + kc) * N + n] = acc;
}
__global__ void bias_fold_final(const float* __restrict__ part, const float* __restrict__ b,
                                float* __restrict__ beff, int N) {
  const int zg = blockIdx.y;
  const int n = blockIdx.x * 256 + (int)threadIdx.x;
  float acc = b[(size_t)zg * N + n];
#pragma unroll
  for (int c = 0; c < BF_KC; ++c) acc += part[((size_t)zg * BF_KC + c) * N + n];
  beff[(size_t)zg * N + n] = acc;
}

// ---- hmean_b[b*400+t][c] = bf16(mean_l hbuf[(b*24+l)*400+t][c]), c<512.
__global__ void mean_h(const unsigned short* __restrict__ h,
                       unsigned short* __restrict__ out) {
  const int i = blockIdx.x * 256 + (int)threadIdx.x;  // quad over [4][400][128]
  if (i >= 4 * 400 * 128) return;
  const int b = i / (400 * 128);
  const int rem = i - b * (400 * 128);
  const int t = rem >> 7, c4 = rem & 127;
  float a0 = 0.f, a1 = 0.f, a2 = 0.f, a3 = 0.f;
  for (int l = 0; l < 24; ++l) {
    ushort4 v = *(const ushort4*)(h + ((size_t)(b * 24 + l) * 400 + t) * 1024 + c4 * 4);
    a0 += bf2f(v.x); a1 += bf2f(v.y); a2 += bf2f(v.z); a3 += bf2f(v.w);
  }
  ushort4 o;
  o.x = f2bf(a0 * (1.f / 24.f));
  o.y = f2bf(a1 * (1.f / 24.f));
  o.z = f2bf(a2 * (1.f / 24.f));
  o.w = f2bf(a3 * (1.f / 24.f));
  *(ushort4*)(out + ((size_t)(b * 400 + t)) * 512 + c4 * 4) = o;
}

// ---- mean over T=400, two-stage split-T (fln path).
template <int TIN>
__global__ void mean_t_part(const void* __restrict__ inv, float* __restrict__ part,
                            int Ns) {
  const int bx = (int)blockIdx.x;
  const int n = bx >> 2, cb = bx & 3;
  const int p = (int)blockIdx.y;
  const int c = cb * 128 + (int)threadIdx.x;
  float acc = 0.f;
  const int t0 = p * 50;
  if (TIN) {
    const unsigned short* in = (const unsigned short*)inv;
    for (int t = t0; t < t0 + 50; ++t) acc += bf2f(in[((size_t)n * 400 + t) * 512 + c]);
  } else {
    const float* in = (const float*)inv;
    for (int t = t0; t < t0 + 50; ++t) acc += in[((size_t)n * 400 + t) * 512 + c];
  }
  part[((size_t)p * Ns + n) * 512 + c] = acc;
}
__global__ void mean_t_fin(const float* __restrict__ part, float* __restrict__ out,
                           int Ns) {
  const int i = (int)blockIdx.x * 256 + (int)threadIdx.x;
  if (i >= Ns * 512) return;
  const int n = i >> 9, c = i & 511;
  float acc = 0.f;
#pragma unroll
  for (int p = 0; p < 8; ++p) acc += part[((size_t)p * Ns + n) * 512 + c];
  out[i] = acc * (1.f / 400.f);
}

// ---- fused fusion + LN: fln[b*400+t] = LN(sum_l rw[b,l]*weighted[b,l,t,:])
__global__ void fuse_ln(const unsigned short* __restrict__ wgt,
                        const float* __restrict__ rw, const float* __restrict__ gam,
                        const float* __restrict__ bet, float* __restrict__ fln) {
  const int row = (int)blockIdx.x;  // b*400 + tt
  const int b = row / 400, tt = row - b * 400;
  const int t = (int)threadIdx.x;
  float a0 = 0.f, a1 = 0.f, a2 = 0.f, a3 = 0.f;
  for (int l = 0; l < 24; ++l) {
    const float wv = rw[b * 24 + l];
    ushort4 v = *(const ushort4*)(wgt + ((size_t)(b * 24 + l) * 400 + tt) * 512 + t * 4);
    a0 += wv * bf2f(v.x); a1 += wv * bf2f(v.y);
    a2 += wv * bf2f(v.z); a3 += wv * bf2f(v.w);
  }
  float s1 = a0 + a1 + a2 + a3;
  float s2 = a0 * a0 + a1 * a1 + a2 * a2 + a3 * a3;
  for (int mlane = 1; mlane < 64; mlane <<= 1) {
    s1 += __shfl_xor(s1, mlane);
    s2 += __shfl_xor(s2, mlane);
  }
  __shared__ float red[4];
  if ((t & 63) == 0) {
    red[t >> 6] = s1;
    red[2 + (t >> 6)] = s2;
  }
  __syncthreads();
  s1 = red[0] + red[1];
  s2 = red[2] + red[3];
  const float mu = s1 * (1.f / 512.f);
  const float var = s2 * (1.f / 512.f) - mu * mu;
  const float rstd = rsqrtf(var + 1e-5f);
  const int c = t * 4;
  float4 o;
  o.x = (a0 - mu) * rstd * gam[c + 0] + bet[c + 0];
  o.y = (a1 - mu) * rstd * gam[c + 1] + bet[c + 1];
  o.z = (a2 - mu) * rstd * gam[c + 2] + bet[c + 2];
  o.w = (a3 - mu) * rstd * gam[c + 3] + bet[c + 3];
  ((float4*)fln)[(size_t)row * 128 + t] = o;
}

// ---- fused LN(a)+LN(b) add: one block per row (4 rows), 128 thr.
__global__ void ln2_add(const float* __restrict__ a, const float* __restrict__ bsrc,
                        const float* __restrict__ gam, const float* __restrict__ bet,
                        float* __restrict__ o1, float* __restrict__ o2) {
  const int row = (int)blockIdx.x;
  const int t = (int)threadIdx.x;
  float4 av = ((const float4*)a)[(size_t)row * 128 + t];
  float4 bv = ((const float4*)bsrc)[(size_t)row * 128 + t];
  float s1a = av.x + av.y + av.z + av.w;
  float s2a = av.x * av.x + av.y * av.y + av.z * av.z + av.w * av.w;
  float s1b = bv.x + bv.y + bv.z + bv.w;
  float s2b = bv.x * bv.x + bv.y * bv.y + bv.z * bv.z + bv.w * bv.w;
  for (int mlane = 1; mlane < 64; mlane <<= 1) {
    s1a += __shfl_xor(s1a, mlane);
    s2a += __shfl_xor(s2a, mlane);
    s1b += __shfl_xor(s1b, mlane);
    s2b += __shfl_xor(s2b, mlane);
  }
  __shared__ float red[8];
  if ((t & 63) == 0) {
    const int wv = t >> 6;
    red[wv] = s1a; red[2 + wv] = s2a; red[4 + wv] = s1b; red[6 + wv] = s2b;
  }
  __syncthreads();
  s1a = red[0] + red[1]; s2a = red[2] + red[3];
  s1b = red[4] + red[5]; s2b = red[6] + red[7];
  const float mua = s1a * (1.f / 512.f);
  const float ra = rsqrtf(s2a * (1.f / 512.f) - mua * mua + 1e-5f);
  const float mub = s1b * (1.f / 512.f);
  const float rb = rsqrtf(s2b * (1.f / 512.f) - mub * mub + 1e-5f);
  const int c = t * 4;
  float4 o;
  o.x = ((av.x - mua) * ra * gam[c + 0] + bet[c + 0]) +
        ((bv.x - mub) * rb * gam[c + 0] + bet[c + 0]);
  o.y = ((av.y - mua) * ra * gam[c + 1] + bet[c + 1]) +
        ((bv.y - mub) * rb * gam[c + 1] + bet[c + 1]);
  o.z = ((av.z - mua) * ra * gam[c + 2] + bet[c + 2]) +
        ((bv.z - mub) * rb * gam[c + 2] + bet[c + 2]);
  o.w = ((av.w - mua) * ra * gam[c + 3] + bet[c + 3]) +
        ((bv.w - mub) * rb * gam[c + 3] + bet[c + 3]);
  ((float4*)o1)[(size_t)row * 128 + t] = o;
  ((float4*)o2)[(size_t)row * 128 + t] = o;
}

// ---------------------------------------------------------------------------
// Wave-per-output GEMV.
// ---------------------------------------------------------------------------
template <int WLAYOUT>
__global__ void gemv_wave(const float* __restrict__ A, const float* __restrict__ Wm,
                          const float* __restrict__ b, float* __restrict__ C, int M, int K,
                          int N, int act) {
  const int wid = (int)(blockIdx.x * (blockDim.x >> 6)) + ((int)threadIdx.x >> 6);
  const int lane = (int)threadIdx.x & 63;
  if (wid >= M * N) return;
  const int row = wid / N, col = wid - row * N;
  const float* a = A + (size_t)row * K;
  float acc = 0.f;
  if (WLAYOUT) {
    const float* wt = Wm + (size_t)col * K;
    for (int k = lane; k < K; k += 64) acc += a[k] * wt[k];
  } else {
    for (int k = lane; k < K; k += 64) acc += a[k] * Wm[(size_t)k * N + col];
  }
#pragma unroll
  for (int d = 1; d < 64; d <<= 1) acc += __shfl_xor(acc, d);
  if (lane == 0) {
    acc += b[col];
    if (act) acc = gelu_f(acc);
    C[wid] = acc;
  }
}

__global__ void routing_k(const float* __restrict__ lr, float* __restrict__ o1,
                          float* __restrict__ o2) {
  const int i = (int)threadIdx.x;
  if (i < 96) {
    const float v = 0.5f / (1.f + __expf(-lr[i] * (1.f / 1.75f))) + (0.5f / 24.f);
    o1[i] = v;
    o2[i] = v;
  }
}

// ---------------------------------------------------------------------------
extern "C" void kernel_launch(void* const* d_in, const int* in_sizes, int n_in,
                              void* d_out, int out_size, void* d_ws, size_t ws_size,
                              hipStream_t stream) {
  const float* x = (const float*)d_in[0];
  const float* mlp_alpha = (const float*)d_in[1];
  const float* s_ln_g = (const float*)d_in[2];
  const float* s_ln_b = (const float*)d_in[3];
  const float* s_w1 = (const float*)d_in[4];
  const float* s_b1 = (const float*)d_in[5];
  const float* s_w2 = (const float*)d_in[6];
  const float* s_b2 = (const float*)d_in[7];
  const float* g_ln_g = (const float*)d_in[8];
  const float* g_ln_b = (const float*)d_in[9];
  const float* g_w1 = (const float*)d_in[10];
  const float* g_b1 = (const float*)d_in[11];
  const float* g_w2 = (const float*)d_in[12];
  const float* g_b2 = (const float*)d_in[13];
  const float* p_ln_g = (const float*)d_in[14];
  const float* p_ln_b = (const float*)d_in[15];
  const float* p_in_w = (const float*)d_in[16];
  const float* p_in_b = (const float*)d_in[17];
  const float* p_out_w = (const float*)d_in[18];
  const float* p_out_b = (const float*)d_in[19];
  const float* r_w1 = (const float*)d_in[20];
  const float* r_b1 = (const float*)d_in[21];
  const float* r_w2 = (const float*)d_in[22];
  const float* r_b2 = (const float*)d_in[23];
  const float* pn_g = (const float*)d_in[24];
  const float* pn_b = (const float*)d_in[25];
  const float* pnf_g = (const float*)d_in[26];
  const float* pnf_b = (const float*)d_in[27];
  const float* c_w1 = (const float*)d_in[28];
  const float* c_b1 = (const float*)d_in[29];
  const float* c_w2 = (const float*)d_in[30];
  const float* c_b2 = (const float*)d_in[31];
  const float* c_w3 = (const float*)d_in[32];
  const float* c_b3 = (const float*)d_in[33];

  float* out = (float*)d_out;  // [logits 8][routing 96][fused_all 2048][time_pooled 49152]
  uint8_t* ws = (uint8_t*)d_ws;

  size_t off = 0;
  auto alloc = [&](size_t bytes) -> size_t {
    size_t o = off;
    off += (bytes + 255) & ~(size_t)255;
    return o;
  };
  const size_t off_xhat = alloc(38400ull * 1024 * 2);  // bf16
  const size_t off_h = alloc(38400ull * 1024 * 2);     // bf16 [gelu(sh)|a*gelu(gr)]
  const size_t off_weighted = alloc(38400ull * 512 * 2);
  const size_t off_qk = alloc(38400ull * 1024 * 2);
  const size_t off_pooled = alloc(96ull * 512 * 4);
  const size_t off_rh = alloc(96ull * 128 * 4);
  const size_t off_lr = alloc(96ull * 4);
  const size_t off_rw = alloc(96ull * 4);
  const size_t off_hmean = alloc(1600ull * 512 * 2);
  const size_t off_smb = alloc(1600ull * 512 * 2);
  const size_t off_wn2 = alloc(1600ull * 512 * 2);
  const size_t off_qk2 = alloc(1600ull * 1024 * 2);
  const size_t off_vbuf2 = alloc(1600ull * 512 * 2);
  const size_t off_vt2 = alloc(4ull * 2 * 256 * 400 * 2);
  const size_t off_pooled2 = alloc(4ull * 512 * 4);
  const size_t off_tctx = alloc(4ull * 512 * 4);
  const size_t off_fln = alloc(4ull * 400 * 512 * 4);
  const size_t off_fvec = alloc(4ull * 512 * 4);
  const size_t off_fall = alloc(4ull * 512 * 4);
  const size_t off_c1 = alloc(4ull * 256 * 4);
  const size_t off_c2 = alloc(4ull * 128 * 4);
  const size_t off_sw1T = alloc(512ull * 1024 * 2);
  const size_t off_sw2T = alloc(512ull * 512 * 2);
  const size_t off_gw1T = alloc(4ull * 512 * 1024 * 2);
  const size_t off_gw2T = alloc(4ull * 512 * 512 * 2);
  const size_t off_pinT = alloc(1536ull * 512 * 2);
  const size_t off_wc2 = alloc(4ull * 512 * 1024 * 2);  // wcomb2
  const size_t off_sb1e = alloc(512ull * 4);
  const size_t off_gb1e = alloc(4ull * 512 * 4);
  const size_t off_pinbe = alloc(1536ull * 4);
  const size_t off_beff2 = alloc(24ull * 512 * 4);
  const size_t off_bfp_s = alloc((size_t)BF_KC * 512 * 4);
  const size_t off_bfp_g = alloc(4ull * BF_KC * 512 * 4);
  const size_t off_bfp_p = alloc((size_t)BF_KC * 1536 * 4);
  const size_t off_powT = alloc(512ull * 512 * 4);
  const size_t off_rw1T = alloc(128ull * 512 * 4);
  const size_t off_cw1T = alloc(256ull * 512 * 4);
  const size_t off_cw2T = alloc(128ull * 256 * 4);
  const size_t off_mtp = alloc(8ull * 96 * 512 * 4);
  const size_t off_wstats = alloc(38400ull * 8);       // float2 per row (R14)
  const size_t off_csp = alloc(1536ull * 4);           // colsum(pinT) (R14)
  const size_t off_pp1 = alloc(96ull * 14 * 256 * 4);  // attn pool partials
  const size_t off_pp2 = alloc(4ull * 14 * 256 * 4);
  // overlays (lifetimes disjoint in the launch sequence below)
  const size_t off_vbuf = off_xhat + 38400ull * 512 * 2;// V natural <- xhat 2nd half
  const size_t off_vt = off_h + 38400ull * 512 * 2;     // V^T <- hbuf 2nd half
  if (off > ws_size) return;  // workspace too small: bail cleanly

  unsigned short* xhat = (unsigned short*)(ws + off_xhat);
  unsigned short* hbuf = (unsigned short*)(ws + off_h);
  unsigned short* weighted = (unsigned short*)(ws + off_weighted);
  unsigned short* qk = (unsigned short*)(ws + off_qk);
  unsigned short* vbuf = (unsigned short*)(ws + off_vbuf);
  unsigned short* vt = (unsigned short*)(ws + off_vt);
  float* pooled = (float*)(ws + off_pooled);
  float* rh = (float*)(ws + off_rh);
  float* lr = (float*)(ws + off_lr);
  float* rw = (float*)(ws + off_rw);
  unsigned short* hmean_b = (unsigned short*)(ws + off_hmean);
  unsigned short* smean_b = (unsigned short*)(ws + off_smb);
  unsigned short* wn2 = (unsigned short*)(ws + off_wn2);
  unsigned short* qk2 = (unsigned short*)(ws + off_qk2);
  unsigned short* vbuf2 = (unsigned short*)(ws + off_vbuf2);
  unsigned short* vt2 = (unsigned short*)(ws + off_vt2);
  float* pooled2 = (float*)(ws + off_pooled2);
  float* tctx = (float*)(ws + off_tctx);
  float* fln = (float*)(ws + off_fln);
  float* fvec = (float*)(ws + off_fvec);
  float* fall = (float*)(ws + off_fall);
  float* c1 = (float*)(ws + off_c1);
  float* c2 = (float*)(ws + off_c2);
  unsigned short* sw1T = (unsigned short*)(ws + off_sw1T);
  unsigned short* sw2T = (unsigned short*)(ws + off_sw2T);
  unsigned short* gw1T = (unsigned short*)(ws + off_gw1T);
  unsigned short* gw2T = (unsigned short*)(ws + off_gw2T);
  unsigned short* pinT = (unsigned short*)(ws + off_pinT);
  unsigned short* wcomb2 = (unsigned short*)(ws + off_wc2);
  float* sb1e = (float*)(ws + off_sb1e);
  float* gb1e = (float*)(ws + off_gb1e);
  float* pinbe = (float*)(ws + off_pinbe);
  float* beff2 = (float*)(ws + off_beff2);
  float* bfp_s = (float*)(ws + off_bfp_s);
  float* bfp_g = (float*)(ws + off_bfp_g);
  float* bfp_p = (float*)(ws + off_bfp_p);
  float* powT = (float*)(ws + off_powT);
  float* rw1T = (float*)(ws + off_rw1T);
  float* cw1T = (float*)(ws + off_cw1T);
  float* cw2T = (float*)(ws + off_cw2T);
  float* mtp = (float*)(ws + off_mtp);
  float2* wstats = (float2*)(ws + off_wstats);
  float* csP = (float*)(ws + off_csp);
  float* pp1 = (float*)(ws + off_pp1);
  float* pp2 = (float*)(ws + off_pp2);

  // ---- weight prep
  transpose_w<<<dim3(32, 16, 1), dim3(32, 8), 0, stream>>>(s_w1, s_ln_g, sw1T, 1024, 512);
  transpose_w<<<dim3(16, 16, 1), dim3(32, 8), 0, stream>>>(s_w2, (const float*)0, sw2T, 512, 512);
  transpose_w<<<dim3(32, 16, 4), dim3(32, 8), 0, stream>>>(g_w1, g_ln_g, gw1T, 1024, 512);
  transpose_w<<<dim3(16, 16, 4), dim3(32, 8), 0, stream>>>(g_w2, (const float*)0, gw2T, 512, 512);
  transpose_w<<<dim3(16, 48, 1), dim3(32, 8), 0, stream>>>(p_in_w, p_ln_g, pinT, 512, 1536);
  transpose_wf<<<dim3(16, 16), dim3(32, 8), 0, stream>>>(p_out_w, powT, 512, 512);
  transpose_wf<<<dim3(16, 4), dim3(32, 8), 0, stream>>>(r_w1, rw1T, 512, 128);
  transpose_wf<<<dim3(16, 8), dim3(32, 8), 0, stream>>>(c_w1, cw1T, 512, 256);
  transpose_wf<<<dim3(8, 4), dim3(32, 8), 0, stream>>>(c_w2, cw2T, 256, 128);
  build_wcomb2<<<2048, 256, 0, stream>>>(sw2T, gw2T, wcomb2);
  build_beff2<<<24, 512, 0, stream>>>(s_b2, g_b2, mlp_alpha, beff2);
  row_sum_bf16<<<384, 256, 0, stream>>>(pinT, csP, 512);  // colsum(pinT) (R14)
  bias_fold_part<<<dim3(2, BF_KC, 1), 256, 0, stream>>>(s_w1, s_ln_b, bfp_s, 1024, 512);
  bias_fold_final<<<dim3(2, 1), 256, 0, stream>>>(bfp_s, s_b1, sb1e, 512);
  bias_fold_part<<<dim3(2, BF_KC, 4), 256, 0, stream>>>(g_w1, g_ln_b, bfp_g, 1024, 512);
  bias_fold_final<<<dim3(2, 4), 256, 0, stream>>>(bfp_g, g_b1, gb1e, 512);
  bias_fold_part<<<dim3(6, BF_KC, 1), 256, 0, stream>>>(p_in_w, p_ln_b, bfp_p, 512, 1536);
  bias_fold_final<<<dim3(6, 1), 256, 0, stream>>>(bfp_p, p_in_b, pinbe, 1536);

  // ---- xhat = normalize(x) (no affine; folded)
  ln_rows<0, 0><<<38400, 256, 0, stream>>>(x, xhat, (const float*)0, (const float*)0, 1024);

  // ---- merged MLP layer 1: hbuf = [gelu(xhat@sw1+sb1e) | a_l*gelu(xhat@gw1+gb1e)]
  gemm_bt<4, 1><<<dim3(19, 8, 16), 256, 0, stream>>>(xhat, sw1T, sb1e, hbuf, gw1T, gb1e,
      mlp_alpha, (unsigned short*)0, 1024, 1024, 1024, 2400);

  // ---- merged MLP layer 2: weighted = hbuf @ wcomb2[grp] + beff2[l]
  gemm_bt<5, 1><<<dim3(19, 4, 16), 256, 0, stream>>>(hbuf, wcomb2, (const float*)0,
      weighted, (const unsigned short*)0, beff2, (const float*)0, (unsigned short*)0,
      1024, 512, 512, 2400);

  // ---- shared_mean via mean/matmul commutation: smean = mean_l(h_s)@sw2 + s_b2
  mean_h<<<800, 256, 0, stream>>>(hbuf, hmean_b);
  gemm_bt<0, 0><<<dim3(13, 4, 1), 256, 0, stream>>>(hmean_b, sw2T, s_b2, smean_b,
      (const unsigned short*)0, (const float*)0, (const float*)0, (unsigned short*)0,
      512, 512, 512, 1600);

  // ---- attention pool over weighted (96 streams); LN commuted into gemm (R14)
  row_stats<<<38400, 128, 0, stream>>>(weighted, wstats);
  gemm_bt<6, 0><<<dim3(300, 12, 1), 256, 0, stream>>>(weighted, pinT, pinbe, qk,
      (const unsigned short*)0, (const float*)wstats, csP, vbuf, 512, 1536, 1024,
      38400);
  transpose_v<<<dim3(13, 8, 192), dim3(32, 8), 0, stream>>>(vbuf, vt);
  attn_fwd<<<dim3(14 * 96), 256, 0, stream>>>(qk, vt, pp1);
  pool_fin<<<192, 256, 0, stream>>>(pp1, pooled, 96);
  gemv_wave<1><<<12288, 256, 0, stream>>>(pooled, powT, p_out_b, out + 2152, 96, 512, 512, 0);

  // ---- router
  gemv_wave<1><<<3072, 256, 0, stream>>>(out + 2152, rw1T, r_b1, rh, 96, 512, 128, 1);
  gemv_wave<0><<<24, 256, 0, stream>>>(rh, r_w2, r_b2, lr, 96, 128, 1, 0);
  routing_k<<<1, 128, 0, stream>>>(lr, out + 8, rw);

  // ---- fusion (fused weighted-sum + LN, then split-T mean)
  fuse_ln<<<1600, 128, 0, stream>>>(weighted, rw, pn_g, pn_b, fln);
  mean_t_part<0><<<dim3(4 * 4, 8), 128, 0, stream>>>(fln, mtp, 4);
  mean_t_fin<<<8, 256, 0, stream>>>(mtp, fvec, 4);

  // ---- time_ctx = attn_pool(shared_mean) (4 streams; small path unchanged)
  ln_rows<1, 0><<<1600, 128, 0, stream>>>(smean_b, wn2, (const float*)0, (const float*)0, 512);
  gemm_bt<3, 0><<<dim3(13, 12, 1), 256, 0, stream>>>(wn2, pinT, pinbe, qk2,
      (const unsigned short*)0, (const float*)0, (const float*)0, vbuf2, 512, 1536, 1024,
      1600);
  transpose_v<<<dim3(13, 8, 8), dim3(32, 8), 0, stream>>>(vbuf2, vt2);
  attn_fwd<<<dim3(14 * 4), 256, 0, stream>>>(qk2, vt2, pp2);
  pool_fin<<<8, 256, 0, stream>>>(pp2, pooled2, 4);
  gemv_wave<1><<<512, 256, 0, stream>>>(pooled2, powT, p_out_b, tctx, 4, 512, 512, 0);

  // ---- fused_all = LN(fvec) + LN(tctx)
  ln2_add<<<4, 128, 0, stream>>>(fvec, tctx, pnf_g, pnf_b, out + 104, fall);

  // ---- classifier
  gemv_wave<1><<<256, 256, 0, stream>>>(fall, cw1T, c_b1, c1, 4, 512, 256, 1);
  gemv_wave<1><<<128, 256, 0, stream>>>(c1, cw2T, c_b2, c2, 4, 256, 128, 1);
  gemv_wave<0><<<2, 256, 0, stream>>>(c2, c_w3, c_b3, out, 4, 128, 2, 0);
}